// Round 3
// baseline (514.318 us; speedup 1.0000x reference)
//
#include <hip/hip_runtime.h>
#include <math.h>

// B=4, C=256, H=W=64, G=4, Cg=64, P=9. x [B,HW,C] is NHWC already.
// Convs via implicit-GEMM MFMA (bf16 2-term split: hi*hi + hi*lo + lo*hi),
// inputs pre-padded to [66][66][C] split-bf16 in ws -> no border branches.
// R3: latency fixes — 16px/wave tiles (2x waves), register-dbuf A prefetch,
// ring-only zerofill, merged weight prep.

typedef __attribute__((ext_vector_type(8))) short short8;
typedef __attribute__((ext_vector_type(4))) float floatx4;

__device__ __forceinline__ unsigned short f2bf(float f) {
    unsigned u = __float_as_uint(f);
    u = (u + 0x7FFFu + ((u >> 16) & 1u)) >> 16;
    return (unsigned short)u;
}
__device__ __forceinline__ float bf2f(unsigned short h) {
    return __uint_as_float(((unsigned)h) << 16);
}
__device__ __forceinline__ void split2(float v, unsigned short* hi, unsigned short* lo) {
    unsigned short h = f2bf(v);
    *hi = h;
    *lo = f2bf(v - bf2f(h));
}

// ---------------- MFMA implicit-GEMM conv core ----------------
// Padded NHWC input [b][66][66][astride] split bf16. Weights [tap][OCPAD][IC].
// Wave tile: MT*16 pixels x NT*16 oc. Block = 4 waves = MT*64 consecutive px.
// A frag: m=lane&15 -> pixel, k=quad*8+j -> ic. B frag: n=lane&15 -> oc.
// C/D: col(oc)=lane&15, row(pixel)=quad*4+reg.
// ACT: 0 none, 1 gelu(exact), 2 sigmoid. OUTMODE: 0 fp32 NHWC, 1 split-pad bf16.
template<int IC, int MT, int NT, int ACT, int OUTMODE>
__device__ __forceinline__ void conv_core(
    const unsigned short* __restrict__ ah, const unsigned short* __restrict__ al,
    int astride, int icbase,
    const unsigned short* __restrict__ wh, const unsigned short* __restrict__ wl,
    const float* __restrict__ bias,
    int b, int mblock,
    float* __restrict__ outf, int oc_real,
    unsigned short* __restrict__ oh, unsigned short* __restrict__ ol,
    int ostride, int ocbase)
{
    const int OCPAD = NT * 16;
    const int NC = IC / 32;        // 32-ic chunks
    const int TOTAL = 9 * NC;      // flattened tap x chunk iterations (even)
    int wave = threadIdx.x >> 6;
    int lane = threadIdx.x & 63;
    int quad = lane >> 4;
    int l16 = lane & 15;

    int pix0 = (mblock * 4 + wave) * (MT * 16);   // [0,4096)
    int y = pix0 >> 6;
    int x0 = pix0 & 63;

    floatx4 acc[MT][NT];
#pragma unroll
    for (int nt = 0; nt < NT; nt++) {
        float bv = bias[nt * 16 + l16];
#pragma unroll
        for (int mt = 0; mt < MT; mt++) { floatx4 v = {bv, bv, bv, bv}; acc[mt][nt] = v; }
    }

    size_t ibase = (size_t)b * 4356 * astride + icbase + quad * 8;

    // A-fragment address for flattened iteration it
    auto aoff = [&](int it) -> size_t {
        int tap = it / NC;
        int c0 = (it - tap * NC) * 32;
        int kh = tap / 3, kw = tap - kh * 3;
        return ibase + (size_t)((y + kh) * 66 + (x0 + kw) + l16) * astride + c0;
    };

    short8 Ah[2][MT], Al[2][MT];
    {
        size_t r = aoff(0);
#pragma unroll
        for (int mt = 0; mt < MT; mt++) {
            Ah[0][mt] = *(const short8*)(ah + r + (size_t)(mt * 16) * astride);
            Al[0][mt] = *(const short8*)(al + r + (size_t)(mt * 16) * astride);
        }
    }

#pragma unroll 2
    for (int it = 0; it < TOTAL; it++) {
        int cur = it & 1, nxt = cur ^ 1;
        if (it + 1 < TOTAL) {
            size_t r = aoff(it + 1);
#pragma unroll
            for (int mt = 0; mt < MT; mt++) {
                Ah[nxt][mt] = *(const short8*)(ah + r + (size_t)(mt * 16) * astride);
                Al[nxt][mt] = *(const short8*)(al + r + (size_t)(mt * 16) * astride);
            }
        }
        int tap = it / NC;
        int c0 = (it - tap * NC) * 32;
        const unsigned short* pwh = wh + (size_t)(tap * OCPAD + l16) * IC + quad * 8 + c0;
        const unsigned short* pwl = wl + (size_t)(tap * OCPAD + l16) * IC + quad * 8 + c0;
#pragma unroll
        for (int nt = 0; nt < NT; nt++) {
            short8 b_h = *(const short8*)(pwh + (size_t)(nt * 16) * IC);
            short8 b_l = *(const short8*)(pwl + (size_t)(nt * 16) * IC);
#pragma unroll
            for (int mt = 0; mt < MT; mt++) {
                acc[mt][nt] = __builtin_amdgcn_mfma_f32_16x16x32_bf16(Ah[cur][mt], b_h, acc[mt][nt], 0, 0, 0);
                acc[mt][nt] = __builtin_amdgcn_mfma_f32_16x16x32_bf16(Ah[cur][mt], b_l, acc[mt][nt], 0, 0, 0);
                acc[mt][nt] = __builtin_amdgcn_mfma_f32_16x16x32_bf16(Al[cur][mt], b_h, acc[mt][nt], 0, 0, 0);
            }
        }
    }

#pragma unroll
    for (int nt = 0; nt < NT; nt++) {
        int oc = nt * 16 + l16;
#pragma unroll
        for (int mt = 0; mt < MT; mt++) {
#pragma unroll
            for (int r = 0; r < 4; r++) {
                float v = acc[mt][nt][r];
                if (ACT == 1) v = 0.5f * v * (1.0f + erff(v * 0.70710678118654752f));
                else if (ACT == 2) v = 1.0f / (1.0f + expf(-v));
                int px = pix0 + mt * 16 + quad * 4 + r;
                if (OUTMODE == 0) {
                    if (oc < oc_real)
                        outf[((size_t)b * 4096 + px) * oc_real + oc] = v;
                } else {
                    int yy = (px >> 6) + 1, xx = (px & 63) + 1;
                    size_t o = ((size_t)b * 4356 + yy * 66 + xx) * ostride + ocbase + oc;
                    unsigned short hv, lv; split2(v, &hv, &lv);
                    oh[o] = hv; ol[o] = lv;
                }
            }
        }
    }
}

// convA: conv1 (grouped C->C, gelu, ->h1pad) fused with conv3 (256->64, gelu, ->m1pad)
// grid.x = 320: [0,256) conv1 (g=bx>>6, mb=bx&63), [256,320) conv3 (mb=bx-256)
__global__ __launch_bounds__(256) void convA_kernel(
    const unsigned short* __restrict__ xph, const unsigned short* __restrict__ xpl,
    const unsigned short* __restrict__ w1h, const unsigned short* __restrict__ w1l,
    const float* __restrict__ off_b1,
    const unsigned short* __restrict__ w3h, const unsigned short* __restrict__ w3l,
    const float* __restrict__ mod_b1,
    unsigned short* __restrict__ h1h, unsigned short* __restrict__ h1l,
    unsigned short* __restrict__ m1h, unsigned short* __restrict__ m1l)
{
    int b = blockIdx.z;
    if (blockIdx.x < 256) {
        int g = blockIdx.x >> 6;
        int mb = blockIdx.x & 63;
        conv_core<64, 1, 4, 1, 1>(xph, xpl, 256, g * 64,
            w1h + (size_t)g * 9 * 64 * 64, w1l + (size_t)g * 9 * 64 * 64, off_b1 + g * 64,
            b, mb, nullptr, 0, h1h, h1l, 256, g * 64);
    } else {
        int mb = blockIdx.x - 256;
        conv_core<256, 1, 4, 1, 1>(xph, xpl, 256, 0, w3h, w3l, mod_b1,
            b, mb, nullptr, 0, m1h, m1l, 64, 0);
    }
}

// convB: conv2 (256->72, ->offo fp32) fused with conv4 (64->36, sigmoid, ->modo fp32)
// grid.x = 128: [0,64) conv2 (mb=bx), [64,128) conv4 (mb=bx-64)
__global__ __launch_bounds__(256) void convB_kernel(
    const unsigned short* __restrict__ h1h, const unsigned short* __restrict__ h1l,
    const unsigned short* __restrict__ w2h, const unsigned short* __restrict__ w2l,
    const float* __restrict__ b2p,
    const unsigned short* __restrict__ m1h, const unsigned short* __restrict__ m1l,
    const unsigned short* __restrict__ w4h, const unsigned short* __restrict__ w4l,
    const float* __restrict__ b4p,
    float* __restrict__ offo, float* __restrict__ modo)
{
    int b = blockIdx.z;
    if (blockIdx.x < 64) {
        conv_core<256, 1, 5, 0, 0>(h1h, h1l, 256, 0, w2h, w2l, b2p,
            b, blockIdx.x, offo, 72, nullptr, nullptr, 0, 0);
    } else {
        conv_core<64, 1, 3, 2, 0>(m1h, m1l, 64, 0, w4h, w4l, b4p,
            b, blockIdx.x - 64, modo, 36, nullptr, nullptr, 0, 0);
    }
}

// ---------------- prep kernels ----------------
__global__ void prep_x_kernel(const float* __restrict__ x,
                              unsigned short* __restrict__ xph, unsigned short* __restrict__ xpl)
{
    int bid = blockIdx.x;           // b*4356 + i*66 + j
    int c = threadIdx.x;
    int b = bid / 4356;
    int rem = bid - b * 4356;
    int i = rem / 66, j = rem - i * 66;
    float v = 0.f;
    if (i >= 1 && i <= 64 && j >= 1 && j <= 64)
        v = x[((size_t)b * 4096 + (size_t)(i - 1) * 64 + (j - 1)) * 256 + c];
    size_t o = (size_t)bid * 256 + c;
    unsigned short h, l; split2(v, &h, &l);
    xph[o] = h; xpl[o] = l;
}

// zero only the halo ring (260 px/image) of h1pad and m1pad (hi+lo)
__global__ void ring_zero_kernel(unsigned short* __restrict__ h1h, unsigned short* __restrict__ h1l,
                                 unsigned short* __restrict__ m1h, unsigned short* __restrict__ m1l)
{
    int bid = blockIdx.x;           // b*260 + r
    int b = bid / 260;
    int r = bid - b * 260;
    int i, j;
    if (r < 66)       { i = 0;        j = r; }
    else if (r < 132) { i = 65;       j = r - 66; }
    else if (r < 196) { i = r - 131;  j = 0; }     // rows 1..64
    else              { i = r - 195;  j = 65; }
    size_t p = (size_t)b * 4356 + (size_t)i * 66 + j;
    int t = threadIdx.x;
    h1h[p * 256 + t] = 0; h1l[p * 256 + t] = 0;
    if (t < 64) { m1h[p * 64 + t] = 0; m1l[p * 64 + t] = 0; }
}

// merged weight+bias prep. OIHW fp32 -> [g][tap][ocpad][ic] split bf16 (zero-pad oc)
__global__ void prep_w_all_kernel(
    const float* __restrict__ w1, const float* __restrict__ w2,
    const float* __restrict__ w3, const float* __restrict__ w4,
    const float* __restrict__ b2, const float* __restrict__ b4,
    unsigned short* __restrict__ w1h, unsigned short* __restrict__ w1l,
    unsigned short* __restrict__ w2h, unsigned short* __restrict__ w2l,
    unsigned short* __restrict__ w3h, unsigned short* __restrict__ w3l,
    unsigned short* __restrict__ w4h, unsigned short* __restrict__ w4l,
    float* __restrict__ b2p, float* __restrict__ b4p)
{
    const int N1 = 147456, N2 = 184320, N3 = 147456, N4 = 27648;
    int idx = blockIdx.x * 256 + threadIdx.x;
    const float* w; unsigned short *outh, *outl;
    int ocpad, oc_real, ic, base;
    if (idx < N1)                { w = w1; outh = w1h; outl = w1l; ocpad = 64; oc_real = 64; ic = 64;  base = 0; }
    else if (idx < N1 + N2)      { w = w2; outh = w2h; outl = w2l; ocpad = 80; oc_real = 72; ic = 256; base = N1; }
    else if (idx < N1 + N2 + N3) { w = w3; outh = w3h; outl = w3l; ocpad = 64; oc_real = 64; ic = 256; base = N1 + N2; }
    else if (idx < N1 + N2 + N3 + N4) { w = w4; outh = w4h; outl = w4l; ocpad = 48; oc_real = 36; ic = 64; base = N1 + N2 + N3; }
    else {
        int t = idx - (N1 + N2 + N3 + N4);
        if (t < 80) b2p[t] = (t < 72) ? b2[t] : 0.f;
        else if (t < 128) { int u = t - 80; b4p[u] = (u < 36) ? b4[u] : 0.f; }
        return;
    }
    int lidx = idx - base;
    int icx = lidx % ic;
    int r1 = lidx / ic;
    int ocp = r1 % ocpad;
    int r2 = r1 / ocpad;
    int tap = r2 % 9;
    int g = r2 / 9;
    float v = 0.f;
    if (ocp < oc_real) {
        int oc = g * oc_real + ocp;
        v = w[((size_t)oc * ic + icx) * 9 + tap];
    }
    unsigned short h, l; split2(v, &h, &l);
    outh[lidx] = h; outl[lidx] = l;
}

// ---------------- deformable sampling (exact fp32) ----------------
__global__ __launch_bounds__(256) void deform_sample(
    const float* __restrict__ x, const float* __restrict__ off,
    const float* __restrict__ mod, float* __restrict__ out)
{
    const int W = 64;
    int wave = (int)((blockIdx.x * 256u + threadIdx.x) >> 6);
    int lane = (int)(threadIdx.x & 63u);

    int b  = wave >> 14;
    int g  = (wave >> 12) & 3;
    int hw = wave & 4095;
    int hy = hw >> 6;
    int wx = hw & 63;

    float fx = 0.f, fy = 0.f, fm = 0.f;
    int p = lane;
    if (lane < 9) {
        const float* ob = off + ((size_t)(b << 12) + hw) * 72 + g * 18;
        fx = ob[p];
        fy = ob[9 + p];
        fm = mod[((size_t)(b << 12) + hw) * 36 + g * 9 + p];
    }
    float px = fminf(fmaxf((float)wx + (float)(p % 3 - 1) + fx, 0.f), 63.f);
    float py = fminf(fmaxf((float)hy + (float)(p / 3 - 1) + fy, 0.f), 63.f);
    float x0f = floorf(px), y0f = floorf(py);
    float wxf = px - x0f, wyf = py - y0f;
    int x0 = (int)x0f, y0 = (int)y0f;
    int x1 = min(x0 + 1, 63), y1 = min(y0 + 1, 63);

    const float* xb = x + ((size_t)(b << 12)) * 256 + g * 64 + lane;
    float acc = 0.f;
#pragma unroll
    for (int q = 0; q < 9; q++) {
        int   qx0 = __shfl(x0, q);
        int   qx1 = __shfl(x1, q);
        int   qy0 = __shfl(y0, q);
        int   qy1 = __shfl(y1, q);
        float qwx = __shfl(wxf, q);
        float qwy = __shfl(wyf, q);
        float qm  = __shfl(fm, q);
        float v00 = xb[((size_t)(qy0 * W + qx0)) * 256];
        float v01 = xb[((size_t)(qy0 * W + qx1)) * 256];
        float v10 = xb[((size_t)(qy1 * W + qx0)) * 256];
        float v11 = xb[((size_t)(qy1 * W + qx1)) * 256];
        float vv = v00 * (1.f - qwx) * (1.f - qwy)
                 + v01 * qwx * (1.f - qwy)
                 + v10 * (1.f - qwx) * qwy
                 + v11 * qwx * qwy;
        acc += qm * vv;
    }
    out[((size_t)(b << 12) + hw) * 256 + g * 64 + lane] = acc * (1.f / 9.f);
}

extern "C" void kernel_launch(void* const* d_in, const int* in_sizes, int n_in,
                              void* d_out, int out_size, void* d_ws, size_t ws_size,
                              hipStream_t stream)
{
    const float* x      = (const float*)d_in[0];
    const float* off_w1 = (const float*)d_in[1];
    const float* off_b1 = (const float*)d_in[2];
    const float* off_w2 = (const float*)d_in[3];
    const float* off_b2 = (const float*)d_in[4];
    const float* mod_w1 = (const float*)d_in[5];
    const float* mod_b1 = (const float*)d_in[6];
    const float* mod_w2 = (const float*)d_in[7];
    const float* mod_b2 = (const float*)d_in[8];

    // ws layout (ushort units; all counts multiple of 8 -> 16B alignment holds)
    const size_t XP = 4u * 4356u * 256u;   // 4,460,544
    const size_t MP = 4u * 4356u * 64u;    // 1,115,136
    const size_t W1 = 4u * 9u * 64u * 64u; // 147,456
    const size_t W2 = 9u * 80u * 256u;     // 184,320
    const size_t W3 = 9u * 64u * 256u;     // 147,456
    const size_t W4 = 9u * 48u * 64u;      // 27,648

    unsigned short* ws = (unsigned short*)d_ws;
    size_t o = 0;
    unsigned short* xph = ws + o; o += XP;
    unsigned short* xpl = ws + o; o += XP;
    unsigned short* h1h = ws + o; o += XP;
    unsigned short* h1l = ws + o; o += XP;
    unsigned short* m1h = ws + o; o += MP;
    unsigned short* m1l = ws + o; o += MP;
    unsigned short* w1h = ws + o; o += W1;
    unsigned short* w1l = ws + o; o += W1;
    unsigned short* w2h = ws + o; o += W2;
    unsigned short* w2l = ws + o; o += W2;
    unsigned short* w3h = ws + o; o += W3;
    unsigned short* w3l = ws + o; o += W3;
    unsigned short* w4h = ws + o; o += W4;
    unsigned short* w4l = ws + o; o += W4;
    float* fbase = (float*)(ws + o);
    float* b2p  = fbase;
    float* b4p  = fbase + 80;
    float* offo = fbase + 128;
    float* modo = offo + (size_t)4 * 4096 * 72;
    size_t need_bytes = o * 2 + ((size_t)128 + 4u*4096u*72u + 4u*4096u*36u) * 4;
    if (ws_size < need_bytes) return;  // deterministic guard

    ring_zero_kernel<<<4 * 260, 256, 0, stream>>>(h1h, h1l, m1h, m1l);
    prep_x_kernel<<<4 * 4356, 256, 0, stream>>>(x, xph, xpl);
    {
        const int NW = 147456 + 184320 + 147456 + 27648 + 128;
        prep_w_all_kernel<<<(NW + 255) / 256, 256, 0, stream>>>(
            off_w1, off_w2, mod_w1, mod_w2, off_b2, mod_b2,
            w1h, w1l, w2h, w2l, w3h, w3l, w4h, w4l, b2p, b4p);
    }

    convA_kernel<<<dim3(320, 1, 4), 256, 0, stream>>>(xph, xpl, w1h, w1l, off_b1,
                                                      w3h, w3l, mod_b1, h1h, h1l, m1h, m1l);
    convB_kernel<<<dim3(128, 1, 4), 256, 0, stream>>>(h1h, h1l, w2h, w2l, b2p,
                                                      m1h, m1l, w4h, w4l, b4p, offo, modo);
    deform_sample<<<16384, 256, 0, stream>>>(x, offo, modo, (float*)d_out);
}

// Round 4
// 455.953 us; speedup vs baseline: 1.1280x; 1.1280x over previous
//
#include <hip/hip_runtime.h>
#include <math.h>

// B=4, C=256, H=W=64, G=4, Cg=64, P=9. x [B,HW,C] is NHWC already.
// Convs via implicit-GEMM MFMA (bf16 2-term split: hi*hi + hi*lo + lo*hi),
// inputs pre-padded to [66][66][C] split-bf16 in ws -> no border branches.
// R4: MT=2 (revert R3), dbuf A AND B fragments, K-split convB x3 via fp32
// atomics (accumulators aliased over dead xpad region) + finalize kernel.

typedef __attribute__((ext_vector_type(8))) short short8;
typedef __attribute__((ext_vector_type(4))) float floatx4;

__device__ __forceinline__ unsigned short f2bf(float f) {
    unsigned u = __float_as_uint(f);
    u = (u + 0x7FFFu + ((u >> 16) & 1u)) >> 16;
    return (unsigned short)u;
}
__device__ __forceinline__ float bf2f(unsigned short h) {
    return __uint_as_float(((unsigned)h) << 16);
}
__device__ __forceinline__ void split2(float v, unsigned short* hi, unsigned short* lo) {
    unsigned short h = f2bf(v);
    *hi = h;
    *lo = f2bf(v - bf2f(h));
}

// ---------------- MFMA implicit-GEMM conv core ----------------
// Padded NHWC input [b][66][66][astride] split bf16. Weights [tap][OCPAD][IC].
// Wave tile: MT*16 pixels x NT*16 oc. Block = 4 waves = MT*64 consecutive px.
// A frag: m=lane&15 -> pixel, k=quad*8+j -> ic. B frag: n=lane&15 -> oc.
// C/D: col(oc)=lane&15, row(pixel)=quad*4+reg.
// ACT: 0 none, 1 gelu(exact), 2 sigmoid.
// OUTMODE: 1 split-pad bf16 (bias+act), 2 fp32 atomicAdd partial (no bias/act).
template<int IC, int MT, int NT, int ACT, int OUTMODE>
__device__ __forceinline__ void conv_core(
    const unsigned short* __restrict__ ah, const unsigned short* __restrict__ al,
    int astride, int icbase,
    const unsigned short* __restrict__ wh, const unsigned short* __restrict__ wl,
    const float* __restrict__ bias,
    int b, int mblock, int tap0, int ntaps,
    unsigned short* __restrict__ oh, unsigned short* __restrict__ ol,
    int ostride, int ocbase,
    float* __restrict__ patom)
{
    const int OCPAD = NT * 16;
    const int NC = IC / 32;
    int wave = threadIdx.x >> 6;
    int lane = threadIdx.x & 63;
    int quad = lane >> 4;
    int l16 = lane & 15;

    int pix0 = (mblock * 4 + wave) * (MT * 16);   // [0,4096)
    int y = pix0 >> 6;
    int x0 = pix0 & 63;

    floatx4 acc[MT][NT];
#pragma unroll
    for (int nt = 0; nt < NT; nt++) {
        float bv = (OUTMODE == 2) ? 0.f : bias[nt * 16 + l16];
#pragma unroll
        for (int mt = 0; mt < MT; mt++) { floatx4 v = {bv, bv, bv, bv}; acc[mt][nt] = v; }
    }

    size_t ibase = (size_t)b * 4356 * astride + icbase + quad * 8;
    const int TOTAL = ntaps * NC;

    short8 Ah[2][MT], Al[2][MT], Bh[2][NT], Bl[2][NT];

    auto load_frag = [&](int slot, int it) {
        int tap = tap0 + it / NC;
        int c0 = (it % NC) * 32;
        int kh = tap / 3, kw = tap - kh * 3;
        size_t r = ibase + (size_t)((y + kh) * 66 + (x0 + kw) + l16) * astride + c0;
#pragma unroll
        for (int mt = 0; mt < MT; mt++) {
            Ah[slot][mt] = *(const short8*)(ah + r + (size_t)(mt * 16) * astride);
            Al[slot][mt] = *(const short8*)(al + r + (size_t)(mt * 16) * astride);
        }
        size_t wr = (size_t)(tap * OCPAD + l16) * IC + quad * 8 + c0;
#pragma unroll
        for (int nt = 0; nt < NT; nt++) {
            Bh[slot][nt] = *(const short8*)(wh + wr + (size_t)(nt * 16) * IC);
            Bl[slot][nt] = *(const short8*)(wl + wr + (size_t)(nt * 16) * IC);
        }
    };

    load_frag(0, 0);
#pragma unroll 2
    for (int it = 0; it < TOTAL; it++) {
        int cur = it & 1, nxt = cur ^ 1;
        if (it + 1 < TOTAL) load_frag(nxt, it + 1);
#pragma unroll
        for (int nt = 0; nt < NT; nt++) {
#pragma unroll
            for (int mt = 0; mt < MT; mt++) {
                acc[mt][nt] = __builtin_amdgcn_mfma_f32_16x16x32_bf16(Ah[cur][mt], Bh[cur][nt], acc[mt][nt], 0, 0, 0);
                acc[mt][nt] = __builtin_amdgcn_mfma_f32_16x16x32_bf16(Ah[cur][mt], Bl[cur][nt], acc[mt][nt], 0, 0, 0);
                acc[mt][nt] = __builtin_amdgcn_mfma_f32_16x16x32_bf16(Al[cur][mt], Bh[cur][nt], acc[mt][nt], 0, 0, 0);
            }
        }
    }

#pragma unroll
    for (int nt = 0; nt < NT; nt++) {
        int oc = nt * 16 + l16;
#pragma unroll
        for (int mt = 0; mt < MT; mt++) {
#pragma unroll
            for (int r = 0; r < 4; r++) {
                float v = acc[mt][nt][r];
                int px = pix0 + mt * 16 + quad * 4 + r;
                if (OUTMODE == 2) {
                    atomicAdd(patom + ((size_t)b * 4096 + px) * OCPAD + oc, v);
                } else {
                    if (ACT == 1) v = 0.5f * v * (1.0f + erff(v * 0.70710678118654752f));
                    else if (ACT == 2) v = 1.0f / (1.0f + expf(-v));
                    int yy = (px >> 6) + 1, xx = (px & 63) + 1;
                    size_t o = ((size_t)b * 4356 + yy * 66 + xx) * ostride + ocbase + oc;
                    unsigned short hv, lv; split2(v, &hv, &lv);
                    oh[o] = hv; ol[o] = lv;
                }
            }
        }
    }
}

// convA: conv1 (grouped C->C, gelu, ->h1pad) fused with conv3 (256->64, gelu, ->m1pad)
// grid.x = 160: [0,128) conv1 (g=bx>>5, mb=bx&31), [128,160) conv3 (mb=bx-128)
__global__ __launch_bounds__(256, 2) void convA_kernel(
    const unsigned short* __restrict__ xph, const unsigned short* __restrict__ xpl,
    const unsigned short* __restrict__ w1h, const unsigned short* __restrict__ w1l,
    const float* __restrict__ off_b1,
    const unsigned short* __restrict__ w3h, const unsigned short* __restrict__ w3l,
    const float* __restrict__ mod_b1,
    unsigned short* __restrict__ h1h, unsigned short* __restrict__ h1l,
    unsigned short* __restrict__ m1h, unsigned short* __restrict__ m1l)
{
    int b = blockIdx.z;
    if (blockIdx.x < 128) {
        int g = blockIdx.x >> 5;
        int mb = blockIdx.x & 31;
        conv_core<64, 2, 4, 1, 1>(xph, xpl, 256, g * 64,
            w1h + (size_t)g * 9 * 64 * 64, w1l + (size_t)g * 9 * 64 * 64, off_b1 + g * 64,
            b, mb, 0, 9, h1h, h1l, 256, g * 64, nullptr);
    } else {
        int mb = blockIdx.x - 128;
        conv_core<256, 2, 4, 1, 1>(xph, xpl, 256, 0, w3h, w3l, mod_b1,
            b, mb, 0, 9, m1h, m1l, 64, 0, nullptr);
    }
}

// convB: conv2 (256->80pad, K-split x3 -> P2a atomics) fused with
//        conv4 (64->48pad, K-split x3 -> P4a atomics)
// grid.x = 192: [0,96) conv2 (ks=bx>>5, mb=bx&31), [96,192) conv4
__global__ __launch_bounds__(256, 2) void convB_kernel(
    const unsigned short* __restrict__ h1h, const unsigned short* __restrict__ h1l,
    const unsigned short* __restrict__ w2h, const unsigned short* __restrict__ w2l,
    const unsigned short* __restrict__ m1h, const unsigned short* __restrict__ m1l,
    const unsigned short* __restrict__ w4h, const unsigned short* __restrict__ w4l,
    float* __restrict__ P2a, float* __restrict__ P4a)
{
    int b = blockIdx.z;
    if (blockIdx.x < 96) {
        int ks = blockIdx.x >> 5;
        int mb = blockIdx.x & 31;
        conv_core<256, 2, 5, 0, 2>(h1h, h1l, 256, 0, w2h, w2l, nullptr,
            b, mb, ks * 3, 3, nullptr, nullptr, 0, 0, P2a);
    } else {
        int t = blockIdx.x - 96;
        int ks = t >> 5;
        int mb = t & 31;
        conv_core<64, 2, 3, 0, 2>(m1h, m1l, 64, 0, w4h, w4l, nullptr,
            b, mb, ks * 3, 3, nullptr, nullptr, 0, 0, P4a);
    }
}

// finalize: offo = P2a + b2 ; modo = sigmoid(P4a + b4)
__global__ __launch_bounds__(128) void finalize_kernel(
    const float* __restrict__ P2a, const float* __restrict__ P4a,
    const float* __restrict__ b2, const float* __restrict__ b4,
    float* __restrict__ offo, float* __restrict__ modo)
{
    size_t p = blockIdx.x;   // b*4096+hw
    int t = threadIdx.x;
    if (t < 80) {
        if (t < 72) offo[p * 72 + t] = P2a[p * 80 + t] + b2[t];
    } else {
        int u = t - 80;
        if (u < 36) {
            float v = P4a[p * 48 + u] + b4[u];
            modo[p * 36 + u] = 1.0f / (1.0f + expf(-v));
        }
    }
}

// ---------------- prep kernels ----------------
__global__ void prep_x_kernel(const float* __restrict__ x,
                              unsigned short* __restrict__ xph, unsigned short* __restrict__ xpl)
{
    int bid = blockIdx.x;           // b*4356 + i*66 + j
    int c = threadIdx.x;
    int b = bid / 4356;
    int rem = bid - b * 4356;
    int i = rem / 66, j = rem - i * 66;
    float v = 0.f;
    if (i >= 1 && i <= 64 && j >= 1 && j <= 64)
        v = x[((size_t)b * 4096 + (size_t)(i - 1) * 64 + (j - 1)) * 256 + c];
    size_t o = (size_t)bid * 256 + c;
    unsigned short h, l; split2(v, &h, &l);
    xph[o] = h; xpl[o] = l;
}

// zero only the halo ring (260 px/image) of h1pad and m1pad (hi+lo)
__global__ void ring_zero_kernel(unsigned short* __restrict__ h1h, unsigned short* __restrict__ h1l,
                                 unsigned short* __restrict__ m1h, unsigned short* __restrict__ m1l)
{
    int bid = blockIdx.x;           // b*260 + r
    int b = bid / 260;
    int r = bid - b * 260;
    int i, j;
    if (r < 66)       { i = 0;        j = r; }
    else if (r < 132) { i = 65;       j = r - 66; }
    else if (r < 196) { i = r - 131;  j = 0; }     // rows 1..64
    else              { i = r - 195;  j = 65; }
    size_t p = (size_t)b * 4356 + (size_t)i * 66 + j;
    int t = threadIdx.x;
    h1h[p * 256 + t] = 0; h1l[p * 256 + t] = 0;
    if (t < 64) { m1h[p * 64 + t] = 0; m1l[p * 64 + t] = 0; }
}

__global__ void zerofill_kernel(uint4* __restrict__ p, int n)
{
    int i = blockIdx.x * 256 + threadIdx.x;
    if (i < n) p[i] = make_uint4(0u, 0u, 0u, 0u);
}

// merged weight prep. OIHW fp32 -> [g][tap][ocpad][ic] split bf16 (zero-pad oc)
__global__ void prep_w_all_kernel(
    const float* __restrict__ w1, const float* __restrict__ w2,
    const float* __restrict__ w3, const float* __restrict__ w4,
    unsigned short* __restrict__ w1h, unsigned short* __restrict__ w1l,
    unsigned short* __restrict__ w2h, unsigned short* __restrict__ w2l,
    unsigned short* __restrict__ w3h, unsigned short* __restrict__ w3l,
    unsigned short* __restrict__ w4h, unsigned short* __restrict__ w4l)
{
    const int N1 = 147456, N2 = 184320, N3 = 147456, N4 = 27648;
    int idx = blockIdx.x * 256 + threadIdx.x;
    const float* w; unsigned short *outh, *outl;
    int ocpad, oc_real, ic, base;
    if (idx < N1)                { w = w1; outh = w1h; outl = w1l; ocpad = 64; oc_real = 64; ic = 64;  base = 0; }
    else if (idx < N1 + N2)      { w = w2; outh = w2h; outl = w2l; ocpad = 80; oc_real = 72; ic = 256; base = N1; }
    else if (idx < N1 + N2 + N3) { w = w3; outh = w3h; outl = w3l; ocpad = 64; oc_real = 64; ic = 256; base = N1 + N2; }
    else if (idx < N1 + N2 + N3 + N4) { w = w4; outh = w4h; outl = w4l; ocpad = 48; oc_real = 36; ic = 64; base = N1 + N2 + N3; }
    else return;
    int lidx = idx - base;
    int icx = lidx % ic;
    int r1 = lidx / ic;
    int ocp = r1 % ocpad;
    int r2 = r1 / ocpad;
    int tap = r2 % 9;
    int g = r2 / 9;
    float v = 0.f;
    if (ocp < oc_real) {
        int oc = g * oc_real + ocp;
        v = w[((size_t)oc * ic + icx) * 9 + tap];
    }
    unsigned short h, l; split2(v, &h, &l);
    outh[lidx] = h; outl[lidx] = l;
}

// ---------------- deformable sampling (exact fp32) ----------------
__global__ __launch_bounds__(256) void deform_sample(
    const float* __restrict__ x, const float* __restrict__ off,
    const float* __restrict__ mod, float* __restrict__ out)
{
    const int W = 64;
    int wave = (int)((blockIdx.x * 256u + threadIdx.x) >> 6);
    int lane = (int)(threadIdx.x & 63u);

    int b  = wave >> 14;
    int g  = (wave >> 12) & 3;
    int hw = wave & 4095;
    int hy = hw >> 6;
    int wx = hw & 63;

    float fx = 0.f, fy = 0.f, fm = 0.f;
    int p = lane;
    if (lane < 9) {
        const float* ob = off + ((size_t)(b << 12) + hw) * 72 + g * 18;
        fx = ob[p];
        fy = ob[9 + p];
        fm = mod[((size_t)(b << 12) + hw) * 36 + g * 9 + p];
    }
    float px = fminf(fmaxf((float)wx + (float)(p % 3 - 1) + fx, 0.f), 63.f);
    float py = fminf(fmaxf((float)hy + (float)(p / 3 - 1) + fy, 0.f), 63.f);
    float x0f = floorf(px), y0f = floorf(py);
    float wxf = px - x0f, wyf = py - y0f;
    int x0 = (int)x0f, y0 = (int)y0f;
    int x1 = min(x0 + 1, 63), y1 = min(y0 + 1, 63);

    const float* xb = x + ((size_t)(b << 12)) * 256 + g * 64 + lane;
    float acc = 0.f;
#pragma unroll
    for (int q = 0; q < 9; q++) {
        int   qx0 = __shfl(x0, q);
        int   qx1 = __shfl(x1, q);
        int   qy0 = __shfl(y0, q);
        int   qy1 = __shfl(y1, q);
        float qwx = __shfl(wxf, q);
        float qwy = __shfl(wyf, q);
        float qm  = __shfl(fm, q);
        float v00 = xb[((size_t)(qy0 * W + qx0)) * 256];
        float v01 = xb[((size_t)(qy0 * W + qx1)) * 256];
        float v10 = xb[((size_t)(qy1 * W + qx0)) * 256];
        float v11 = xb[((size_t)(qy1 * W + qx1)) * 256];
        float vv = v00 * (1.f - qwx) * (1.f - qwy)
                 + v01 * qwx * (1.f - qwy)
                 + v10 * (1.f - qwx) * qwy
                 + v11 * qwx * qwy;
        acc += qm * vv;
    }
    out[((size_t)(b << 12) + hw) * 256 + g * 64 + lane] = acc * (1.f / 9.f);
}

extern "C" void kernel_launch(void* const* d_in, const int* in_sizes, int n_in,
                              void* d_out, int out_size, void* d_ws, size_t ws_size,
                              hipStream_t stream)
{
    const float* x      = (const float*)d_in[0];
    const float* off_w1 = (const float*)d_in[1];
    const float* off_b1 = (const float*)d_in[2];
    const float* off_w2 = (const float*)d_in[3];
    const float* off_b2 = (const float*)d_in[4];
    const float* mod_w1 = (const float*)d_in[5];
    const float* mod_b1 = (const float*)d_in[6];
    const float* mod_w2 = (const float*)d_in[7];
    const float* mod_b2 = (const float*)d_in[8];

    // ws layout (ushort units; all counts multiple of 8 -> 16B alignment holds)
    const size_t XP = 4u * 4356u * 256u;   // 4,460,544
    const size_t MP = 4u * 4356u * 64u;    // 1,115,136
    const size_t W1 = 4u * 9u * 64u * 64u; // 147,456
    const size_t W2 = 9u * 80u * 256u;     // 184,320
    const size_t W3 = 9u * 64u * 256u;     // 147,456
    const size_t W4 = 9u * 48u * 64u;      // 27,648

    unsigned short* ws = (unsigned short*)d_ws;
    size_t o = 0;
    unsigned short* xph = ws + o; o += XP;
    unsigned short* xpl = ws + o; o += XP;
    unsigned short* h1h = ws + o; o += XP;
    unsigned short* h1l = ws + o; o += XP;
    unsigned short* m1h = ws + o; o += MP;
    unsigned short* m1l = ws + o; o += MP;
    unsigned short* w1h = ws + o; o += W1;
    unsigned short* w1l = ws + o; o += W1;
    unsigned short* w2h = ws + o; o += W2;
    unsigned short* w2l = ws + o; o += W2;
    unsigned short* w3h = ws + o; o += W3;
    unsigned short* w3l = ws + o; o += W3;
    unsigned short* w4h = ws + o; o += W4;
    unsigned short* w4l = ws + o; o += W4;
    float* fbase = (float*)(ws + o);
    float* offo = fbase;                             // [4,4096,72]
    float* modo = offo + (size_t)4 * 4096 * 72;      // [4,4096,36]
    // K-split accumulators ALIAS the xpad region (dead after convA):
    float* P2a = (float*)xph;                        // [4*4096][80] = 1,310,720 floats
    float* P4a = P2a + (size_t)4 * 4096 * 80;        // [4*4096][48] =   786,432 floats
    // (P2a+P4a = 2,097,152 floats = 8.4 MB <= xph+xpl region = 17.8 MB)
    size_t need_bytes = o * 2 + ((size_t)4 * 4096 * 72 + (size_t)4 * 4096 * 36) * 4;
    if (ws_size < need_bytes) return;  // deterministic guard

    ring_zero_kernel<<<4 * 260, 256, 0, stream>>>(h1h, h1l, m1h, m1l);
    prep_x_kernel<<<4 * 4356, 256, 0, stream>>>(x, xph, xpl);
    {
        const int NW = 147456 + 184320 + 147456 + 27648;
        prep_w_all_kernel<<<(NW + 255) / 256, 256, 0, stream>>>(
            off_w1, off_w2, mod_w1, mod_w2,
            w1h, w1l, w2h, w2l, w3h, w3l, w4h, w4l);
    }

    convA_kernel<<<dim3(160, 1, 4), 256, 0, stream>>>(xph, xpl, w1h, w1l, off_b1,
                                                      w3h, w3l, mod_b1, h1h, h1l, m1h, m1l);
    // xpad now dead -> zero the aliased K-split accumulators
    zerofill_kernel<<<(2097152 / 4 + 255) / 256, 256, 0, stream>>>((uint4*)P2a, 2097152 / 4);
    convB_kernel<<<dim3(192, 1, 4), 256, 0, stream>>>(h1h, h1l, w2h, w2l,
                                                      m1h, m1l, w4h, w4l, P2a, P4a);
    finalize_kernel<<<4 * 4096, 128, 0, stream>>>(P2a, P4a, off_b2, mod_b2, offo, modo);
    deform_sample<<<16384, 256, 0, stream>>>(x, offo, modo, (float*)d_out);
}

// Round 5
// 299.912 us; speedup vs baseline: 1.7149x; 1.5203x over previous
//
#include <hip/hip_runtime.h>
#include <math.h>

// B=4, C=256, H=W=64, G=4, Cg=64, P=9. x [B,HW,C] is NHWC already.
// Convs via implicit-GEMM MFMA (bf16 2-term split: hi*hi + hi*lo + lo*hi).
// R5: CHUNKED LAYOUT — activations [ch][b][66*66 px][32ic], weights
// [ch][tap][OCPAD][32ic] -> every A/B fragment load is 1KB contiguous
// (was 16 scattered 64B lines with the NHWC-strided layout).
// Keeps R4: MT=2, dbuf A+B, K-split convB x3 via fp32 atomics.

typedef __attribute__((ext_vector_type(8))) short short8;
typedef __attribute__((ext_vector_type(4))) float floatx4;

__device__ __forceinline__ unsigned short f2bf(float f) {
    unsigned u = __float_as_uint(f);
    u = (u + 0x7FFFu + ((u >> 16) & 1u)) >> 16;
    return (unsigned short)u;
}
__device__ __forceinline__ float bf2f(unsigned short h) {
    return __uint_as_float(((unsigned)h) << 16);
}
__device__ __forceinline__ void split2(float v, unsigned short* hi, unsigned short* lo) {
    unsigned short h = f2bf(v);
    *hi = h;
    *lo = f2bf(v - bf2f(h));
}

// ---------------- MFMA implicit-GEMM conv core (chunked layout) ----------------
// Activations: [ch][b][4356 px][32] ushort (hi/lo arrays). px = y*66+x, padded.
// Weights: [ch][tap][OCPAD][32] ushort. ch counts 32-ic chunks.
// Wave tile: 32 px x NT*16 oc. Block = 4 waves = 128 consecutive px (2 rows).
// A frag: m=lane&15 -> pixel, k=quad*8+j -> ic. B frag: n=lane&15 -> oc.
// C/D: col(oc)=lane&15, row(pixel)=quad*4+reg.
// ACT: 0 none, 1 gelu(exact), 2 sigmoid.
// OUTMODE: 1 chunked split-bf16 out (bias+act), 2 fp32 atomicAdd partial.
template<int NC, int MT, int NT, int ACT, int OUTMODE>
__device__ __forceinline__ void conv_core(
    const unsigned short* __restrict__ ah, const unsigned short* __restrict__ al,
    int aC0,
    const unsigned short* __restrict__ wh, const unsigned short* __restrict__ wl,
    const float* __restrict__ bias,
    int b, int mblock, int tap0, int ntaps,
    unsigned short* __restrict__ oh, unsigned short* __restrict__ ol,
    int oC0,
    float* __restrict__ patom)
{
    const int OCPAD = NT * 16;
    int wave = threadIdx.x >> 6;
    int lane = threadIdx.x & 63;
    int quad = lane >> 4;
    int l16 = lane & 15;

    int pix0 = (mblock * 4 + wave) * (MT * 16);   // [0,4096)
    int y = pix0 >> 6;
    int x0 = pix0 & 63;

    floatx4 acc[MT][NT];
#pragma unroll
    for (int nt = 0; nt < NT; nt++) {
        float bv = (OUTMODE == 2) ? 0.f : bias[nt * 16 + l16];
#pragma unroll
        for (int mt = 0; mt < MT; mt++) { floatx4 v = {bv, bv, bv, bv}; acc[mt][nt] = v; }
    }

    const int TOTAL = ntaps * NC;
    short8 Ah[2][MT], Al[2][MT], Bh[2][NT], Bl[2][NT];

    auto load_frag = [&](int slot, int it) {
        int tap = tap0 + it / NC;
        int ch = it % NC;
        int kh = tap / 3, kw = tap - kh * 3;
        // A: contiguous 1KB per instruction: pixel stride = 32 ushorts = 64B
        size_t r = ((size_t)((aC0 + ch) * 4 + b) * 4356 + (y + kh) * 66 + (x0 + kw) + l16) * 32 + quad * 8;
#pragma unroll
        for (int mt = 0; mt < MT; mt++) {
            Ah[slot][mt] = *(const short8*)(ah + r + (size_t)(mt * 16) * 32);
            Al[slot][mt] = *(const short8*)(al + r + (size_t)(mt * 16) * 32);
        }
        // B: contiguous 1KB per instruction: oc stride = 32 ushorts = 64B
        size_t wr = ((size_t)(ch * 9 + tap) * OCPAD + l16) * 32 + quad * 8;
#pragma unroll
        for (int nt = 0; nt < NT; nt++) {
            Bh[slot][nt] = *(const short8*)(wh + wr + (size_t)(nt * 16) * 32);
            Bl[slot][nt] = *(const short8*)(wl + wr + (size_t)(nt * 16) * 32);
        }
    };

    load_frag(0, 0);
#pragma unroll 2
    for (int it = 0; it < TOTAL; it++) {
        int cur = it & 1, nxt = cur ^ 1;
        if (it + 1 < TOTAL) load_frag(nxt, it + 1);
#pragma unroll
        for (int nt = 0; nt < NT; nt++) {
#pragma unroll
            for (int mt = 0; mt < MT; mt++) {
                acc[mt][nt] = __builtin_amdgcn_mfma_f32_16x16x32_bf16(Ah[cur][mt], Bh[cur][nt], acc[mt][nt], 0, 0, 0);
                acc[mt][nt] = __builtin_amdgcn_mfma_f32_16x16x32_bf16(Ah[cur][mt], Bl[cur][nt], acc[mt][nt], 0, 0, 0);
                acc[mt][nt] = __builtin_amdgcn_mfma_f32_16x16x32_bf16(Al[cur][mt], Bh[cur][nt], acc[mt][nt], 0, 0, 0);
            }
        }
    }

#pragma unroll
    for (int nt = 0; nt < NT; nt++) {
        int oc = nt * 16 + l16;
#pragma unroll
        for (int mt = 0; mt < MT; mt++) {
#pragma unroll
            for (int r = 0; r < 4; r++) {
                float v = acc[mt][nt][r];
                int px = pix0 + mt * 16 + quad * 4 + r;
                if (OUTMODE == 2) {
                    atomicAdd(patom + ((size_t)b * 4096 + px) * OCPAD + oc, v);
                } else {
                    if (ACT == 1) v = 0.5f * v * (1.0f + erff(v * 0.70710678118654752f));
                    else if (ACT == 2) v = 1.0f / (1.0f + expf(-v));
                    int yy = (px >> 6) + 1, xx = (px & 63) + 1;
                    int och = oC0 + (oc >> 5);
                    size_t o = ((size_t)(och * 4 + b) * 4356 + yy * 66 + xx) * 32 + (oc & 31);
                    unsigned short hv, lv; split2(v, &hv, &lv);
                    oh[o] = hv; ol[o] = lv;
                }
            }
        }
    }
}

// convA: conv1 (grouped C->C, gelu, ->h1pad) fused with conv3 (256->64, gelu, ->m1pad)
// grid.x = 160: [0,128) conv1 (g=bx>>5, mb=bx&31), [128,160) conv3 (mb=bx-128)
__global__ __launch_bounds__(256, 2) void convA_kernel(
    const unsigned short* __restrict__ xph, const unsigned short* __restrict__ xpl,
    const unsigned short* __restrict__ w1h, const unsigned short* __restrict__ w1l,
    const float* __restrict__ off_b1,
    const unsigned short* __restrict__ w3h, const unsigned short* __restrict__ w3l,
    const float* __restrict__ mod_b1,
    unsigned short* __restrict__ h1h, unsigned short* __restrict__ h1l,
    unsigned short* __restrict__ m1h, unsigned short* __restrict__ m1l)
{
    int b = blockIdx.z;
    if (blockIdx.x < 128) {
        int g = blockIdx.x >> 5;
        int mb = blockIdx.x & 31;
        conv_core<2, 2, 4, 1, 1>(xph, xpl, g * 2,
            w1h + (size_t)g * 2 * 9 * 64 * 32, w1l + (size_t)g * 2 * 9 * 64 * 32, off_b1 + g * 64,
            b, mb, 0, 9, h1h, h1l, g * 2, nullptr);
    } else {
        int mb = blockIdx.x - 128;
        conv_core<8, 2, 4, 1, 1>(xph, xpl, 0, w3h, w3l, mod_b1,
            b, mb, 0, 9, m1h, m1l, 0, nullptr);
    }
}

// convB: conv2 (256->80pad, K-split x3 -> P2a atomics) fused with
//        conv4 (64->48pad, K-split x3 -> P4a atomics)
// grid.x = 192: [0,96) conv2 (ks=bx>>5, mb=bx&31), [96,192) conv4
__global__ __launch_bounds__(256, 2) void convB_kernel(
    const unsigned short* __restrict__ h1h, const unsigned short* __restrict__ h1l,
    const unsigned short* __restrict__ w2h, const unsigned short* __restrict__ w2l,
    const unsigned short* __restrict__ m1h, const unsigned short* __restrict__ m1l,
    const unsigned short* __restrict__ w4h, const unsigned short* __restrict__ w4l,
    float* __restrict__ P2a, float* __restrict__ P4a)
{
    int b = blockIdx.z;
    if (blockIdx.x < 96) {
        int ks = blockIdx.x >> 5;
        int mb = blockIdx.x & 31;
        conv_core<8, 2, 5, 0, 2>(h1h, h1l, 0, w2h, w2l, nullptr,
            b, mb, ks * 3, 3, nullptr, nullptr, 0, P2a);
    } else {
        int t = blockIdx.x - 96;
        int ks = t >> 5;
        int mb = t & 31;
        conv_core<2, 2, 3, 0, 2>(m1h, m1l, 0, w4h, w4l, nullptr,
            b, mb, ks * 3, 3, nullptr, nullptr, 0, P4a);
    }
}

// finalize: offo = P2a + b2 ; modo = sigmoid(P4a + b4)
__global__ __launch_bounds__(128) void finalize_kernel(
    const float* __restrict__ P2a, const float* __restrict__ P4a,
    const float* __restrict__ b2, const float* __restrict__ b4,
    float* __restrict__ offo, float* __restrict__ modo)
{
    size_t p = blockIdx.x;   // b*4096+hw
    int t = threadIdx.x;
    if (t < 80) {
        if (t < 72) offo[p * 72 + t] = P2a[p * 80 + t] + b2[t];
    } else {
        int u = t - 80;
        if (u < 36) {
            float v = P4a[p * 48 + u] + b4[u];
            modo[p * 36 + u] = 1.0f / (1.0f + expf(-v));
        }
    }
}

// ---------------- prep kernels ----------------
// x [B,HW,256] -> chunked padded split-bf16: xp[ch][b][4356][32]
__global__ void prep_x_kernel(const float* __restrict__ x,
                              unsigned short* __restrict__ xph, unsigned short* __restrict__ xpl)
{
    int bid = blockIdx.x;           // b*4356 + i*66 + j
    int c = threadIdx.x;
    int b = bid / 4356;
    int rem = bid - b * 4356;
    int i = rem / 66, j = rem - i * 66;
    float v = 0.f;
    if (i >= 1 && i <= 64 && j >= 1 && j <= 64)
        v = x[((size_t)b * 4096 + (size_t)(i - 1) * 64 + (j - 1)) * 256 + c];
    size_t o = ((size_t)((c >> 5) * 4 + b) * 4356 + rem) * 32 + (c & 31);
    unsigned short h, l; split2(v, &h, &l);
    xph[o] = h; xpl[o] = l;
}

// zero only the halo ring (260 px/image) of h1pad (8 chunks) and m1pad (2 chunks)
__global__ void ring_zero_kernel(unsigned short* __restrict__ h1h, unsigned short* __restrict__ h1l,
                                 unsigned short* __restrict__ m1h, unsigned short* __restrict__ m1l)
{
    int bid = blockIdx.x;           // b*260 + r
    int b = bid / 260;
    int r = bid - b * 260;
    int i, j;
    if (r < 66)       { i = 0;        j = r; }
    else if (r < 132) { i = 65;       j = r - 66; }
    else if (r < 196) { i = r - 131;  j = 0; }     // rows 1..64
    else              { i = r - 195;  j = 65; }
    size_t pp = (size_t)i * 66 + j;
    int t = threadIdx.x;
    int ch = t >> 5, sub = t & 31;
    size_t o = ((size_t)(ch * 4 + b) * 4356 + pp) * 32 + sub;
    h1h[o] = 0; h1l[o] = 0;
    if (t < 64) { m1h[o] = 0; m1l[o] = 0; }
}

__global__ void zerofill_kernel(uint4* __restrict__ p, int n)
{
    int i = blockIdx.x * 256 + threadIdx.x;
    if (i < n) p[i] = make_uint4(0u, 0u, 0u, 0u);
}

// merged weight prep. OIHW fp32 -> [g][ch][tap][OCPAD][32] split bf16 (zero-pad oc)
__global__ void prep_w_all_kernel(
    const float* __restrict__ w1, const float* __restrict__ w2,
    const float* __restrict__ w3, const float* __restrict__ w4,
    unsigned short* __restrict__ w1h, unsigned short* __restrict__ w1l,
    unsigned short* __restrict__ w2h, unsigned short* __restrict__ w2l,
    unsigned short* __restrict__ w3h, unsigned short* __restrict__ w3l,
    unsigned short* __restrict__ w4h, unsigned short* __restrict__ w4l)
{
    const int N1 = 147456, N2 = 184320, N3 = 147456, N4 = 27648;
    int idx = blockIdx.x * 256 + threadIdx.x;
    const float* w; unsigned short *outh, *outl;
    int ocpad, oc_real, ic, base;
    if (idx < N1)                { w = w1; outh = w1h; outl = w1l; ocpad = 64; oc_real = 64; ic = 64;  base = 0; }
    else if (idx < N1 + N2)      { w = w2; outh = w2h; outl = w2l; ocpad = 80; oc_real = 72; ic = 256; base = N1; }
    else if (idx < N1 + N2 + N3) { w = w3; outh = w3h; outl = w3l; ocpad = 64; oc_real = 64; ic = 256; base = N1 + N2; }
    else if (idx < N1 + N2 + N3 + N4) { w = w4; outh = w4h; outl = w4l; ocpad = 48; oc_real = 36; ic = 64; base = N1 + N2 + N3; }
    else return;
    int lidx = idx - base;
    // lidx -> [g][ch][tap][ocp][ici]
    int ici = lidx & 31;
    int t1 = lidx >> 5;
    int ocp = t1 % ocpad;
    int t2 = t1 / ocpad;
    int tap = t2 % 9;
    int t3 = t2 / 9;
    int nch = ic >> 5;
    int ch = t3 % nch;
    int g = t3 / nch;
    float v = 0.f;
    if (ocp < oc_real) {
        int oc = g * oc_real + ocp;
        int icx = ch * 32 + ici;
        v = w[((size_t)oc * ic + icx) * 9 + tap];
    }
    unsigned short h, l; split2(v, &h, &l);
    outh[lidx] = h; outl[lidx] = l;
}

// ---------------- deformable sampling (exact fp32) ----------------
__global__ __launch_bounds__(256) void deform_sample(
    const float* __restrict__ x, const float* __restrict__ off,
    const float* __restrict__ mod, float* __restrict__ out)
{
    const int W = 64;
    int wave = (int)((blockIdx.x * 256u + threadIdx.x) >> 6);
    int lane = (int)(threadIdx.x & 63u);

    int b  = wave >> 14;
    int g  = (wave >> 12) & 3;
    int hw = wave & 4095;
    int hy = hw >> 6;
    int wx = hw & 63;

    float fx = 0.f, fy = 0.f, fm = 0.f;
    int p = lane;
    if (lane < 9) {
        const float* ob = off + ((size_t)(b << 12) + hw) * 72 + g * 18;
        fx = ob[p];
        fy = ob[9 + p];
        fm = mod[((size_t)(b << 12) + hw) * 36 + g * 9 + p];
    }
    float px = fminf(fmaxf((float)wx + (float)(p % 3 - 1) + fx, 0.f), 63.f);
    float py = fminf(fmaxf((float)hy + (float)(p / 3 - 1) + fy, 0.f), 63.f);
    float x0f = floorf(px), y0f = floorf(py);
    float wxf = px - x0f, wyf = py - y0f;
    int x0 = (int)x0f, y0 = (int)y0f;
    int x1 = min(x0 + 1, 63), y1 = min(y0 + 1, 63);

    const float* xb = x + ((size_t)(b << 12)) * 256 + g * 64 + lane;
    float acc = 0.f;
#pragma unroll
    for (int q = 0; q < 9; q++) {
        int   qx0 = __shfl(x0, q);
        int   qx1 = __shfl(x1, q);
        int   qy0 = __shfl(y0, q);
        int   qy1 = __shfl(y1, q);
        float qwx = __shfl(wxf, q);
        float qwy = __shfl(wyf, q);
        float qm  = __shfl(fm, q);
        float v00 = xb[((size_t)(qy0 * W + qx0)) * 256];
        float v01 = xb[((size_t)(qy0 * W + qx1)) * 256];
        float v10 = xb[((size_t)(qy1 * W + qx0)) * 256];
        float v11 = xb[((size_t)(qy1 * W + qx1)) * 256];
        float vv = v00 * (1.f - qwx) * (1.f - qwy)
                 + v01 * qwx * (1.f - qwy)
                 + v10 * (1.f - qwx) * qwy
                 + v11 * qwx * qwy;
        acc += qm * vv;
    }
    out[((size_t)(b << 12) + hw) * 256 + g * 64 + lane] = acc * (1.f / 9.f);
}

extern "C" void kernel_launch(void* const* d_in, const int* in_sizes, int n_in,
                              void* d_out, int out_size, void* d_ws, size_t ws_size,
                              hipStream_t stream)
{
    const float* x      = (const float*)d_in[0];
    const float* off_w1 = (const float*)d_in[1];
    const float* off_b1 = (const float*)d_in[2];
    const float* off_w2 = (const float*)d_in[3];
    const float* off_b2 = (const float*)d_in[4];
    const float* mod_w1 = (const float*)d_in[5];
    const float* mod_b1 = (const float*)d_in[6];
    const float* mod_w2 = (const float*)d_in[7];
    const float* mod_b2 = (const float*)d_in[8];

    // ws layout (ushort units; all counts multiple of 8 -> 16B alignment holds)
    const size_t XP = 4u * 4356u * 256u;   // 4,460,544 (8 chunks x 4 b x 4356 x 32)
    const size_t MP = 4u * 4356u * 64u;    // 1,115,136 (2 chunks)
    const size_t W1 = 4u * 2u * 9u * 64u * 32u;  // 147,456
    const size_t W2 = 8u * 9u * 80u * 32u;       // 184,320
    const size_t W3 = 8u * 9u * 64u * 32u;       // 147,456
    const size_t W4 = 2u * 9u * 48u * 32u;       // 27,648

    unsigned short* ws = (unsigned short*)d_ws;
    size_t o = 0;
    unsigned short* xph = ws + o; o += XP;
    unsigned short* xpl = ws + o; o += XP;
    unsigned short* h1h = ws + o; o += XP;
    unsigned short* h1l = ws + o; o += XP;
    unsigned short* m1h = ws + o; o += MP;
    unsigned short* m1l = ws + o; o += MP;
    unsigned short* w1h = ws + o; o += W1;
    unsigned short* w1l = ws + o; o += W1;
    unsigned short* w2h = ws + o; o += W2;
    unsigned short* w2l = ws + o; o += W2;
    unsigned short* w3h = ws + o; o += W3;
    unsigned short* w3l = ws + o; o += W3;
    unsigned short* w4h = ws + o; o += W4;
    unsigned short* w4l = ws + o; o += W4;
    float* fbase = (float*)(ws + o);
    float* offo = fbase;                             // [4,4096,72]
    float* modo = offo + (size_t)4 * 4096 * 72;      // [4,4096,36]
    // K-split accumulators ALIAS the xpad region (dead after convA):
    float* P2a = (float*)xph;                        // [4*4096][80]
    float* P4a = P2a + (size_t)4 * 4096 * 80;        // [4*4096][48]
    size_t need_bytes = o * 2 + ((size_t)4 * 4096 * 72 + (size_t)4 * 4096 * 36) * 4;
    if (ws_size < need_bytes) return;  // deterministic guard

    ring_zero_kernel<<<4 * 260, 256, 0, stream>>>(h1h, h1l, m1h, m1l);
    prep_x_kernel<<<4 * 4356, 256, 0, stream>>>(x, xph, xpl);
    {
        const int NW = 147456 + 184320 + 147456 + 27648;
        prep_w_all_kernel<<<(NW + 255) / 256, 256, 0, stream>>>(
            off_w1, off_w2, mod_w1, mod_w2,
            w1h, w1l, w2h, w2l, w3h, w3l, w4h, w4l);
    }

    convA_kernel<<<dim3(160, 1, 4), 256, 0, stream>>>(xph, xpl, w1h, w1l, off_b1,
                                                      w3h, w3l, mod_b1, h1h, h1l, m1h, m1l);
    // xpad now dead -> zero the aliased K-split accumulators
    zerofill_kernel<<<(2097152 / 4 + 255) / 256, 256, 0, stream>>>((uint4*)P2a, 2097152 / 4);
    convB_kernel<<<dim3(192, 1, 4), 256, 0, stream>>>(h1h, h1l, w2h, w2l,
                                                      m1h, m1l, w4h, w4l, P2a, P4a);
    finalize_kernel<<<4 * 4096, 128, 0, stream>>>(P2a, P4a, off_b2, mod_b2, offo, modo);
    deform_sample<<<16384, 256, 0, stream>>>(x, offo, modo, (float*)d_out);
}

// Round 6
// 299.307 us; speedup vs baseline: 1.7184x; 1.0020x over previous
//
#include <hip/hip_runtime.h>
#include <math.h>

// B=4, C=256, H=W=64, G=4, Cg=64, P=9. x [B,HW,C] is NHWC already.
// Convs via implicit-GEMM MFMA (bf16 2-term split: hi*hi + hi*lo + lo*hi).
// Chunked layout (R5): activations [ch][b][66*66 px][32ic], weights
// [ch][tap][OCPAD][32ic] -> every A/B fragment load is 1KB contiguous.
// R6: K-split convA x3 into disjoint fp32 partial buffers (plain writes,
// deterministic) + finalizeA (sum+bias+gelu+split-bf16). 1920 blocks for
// convA (was 640) -> kills the conv3 occupancy tail seen in R5 counters.

typedef __attribute__((ext_vector_type(8))) short short8;
typedef __attribute__((ext_vector_type(4))) float floatx4;

__device__ __forceinline__ unsigned short f2bf(float f) {
    unsigned u = __float_as_uint(f);
    u = (u + 0x7FFFu + ((u >> 16) & 1u)) >> 16;
    return (unsigned short)u;
}
__device__ __forceinline__ float bf2f(unsigned short h) {
    return __uint_as_float(((unsigned)h) << 16);
}
__device__ __forceinline__ void split2(float v, unsigned short* hi, unsigned short* lo) {
    unsigned short h = f2bf(v);
    *hi = h;
    *lo = f2bf(v - bf2f(h));
}
__device__ __forceinline__ float gelu_exact(float v) {
    return 0.5f * v * (1.0f + erff(v * 0.70710678118654752f));
}

// ---------------- MFMA implicit-GEMM conv core (chunked layout) ----------------
// Activations: [ch][b][4356 px][32] ushort (hi/lo arrays). px = y*66+x, padded.
// Weights: [ch][tap][OCPAD][32] ushort. ch counts 32-ic chunks.
// Wave tile: 32 px x NT*16 oc. Block = 4 waves = 128 consecutive px (2 rows).
// A frag: m=lane&15 -> pixel, k=quad*8+j -> ic. B frag: n=lane&15 -> oc.
// C/D: col(oc)=lane&15, row(pixel)=quad*4+reg.
// ACT: 0 none, 1 gelu(exact), 2 sigmoid.
// OUTMODE: 1 chunked split-bf16 out (bias+act), 2 fp32 atomicAdd partial,
//          3 fp32 plain write partial (row stride orow, col base oc0).
template<int NC, int MT, int NT, int ACT, int OUTMODE>
__device__ __forceinline__ void conv_core(
    const unsigned short* __restrict__ ah, const unsigned short* __restrict__ al,
    int aC0,
    const unsigned short* __restrict__ wh, const unsigned short* __restrict__ wl,
    const float* __restrict__ bias,
    int b, int mblock, int tap0, int ntaps,
    unsigned short* __restrict__ oh, unsigned short* __restrict__ ol,
    int oC0,
    float* __restrict__ pf, int orow, int oc0)
{
    const int OCPAD = NT * 16;
    int wave = threadIdx.x >> 6;
    int lane = threadIdx.x & 63;
    int quad = lane >> 4;
    int l16 = lane & 15;

    int pix0 = (mblock * 4 + wave) * (MT * 16);   // [0,4096)
    int y = pix0 >> 6;
    int x0 = pix0 & 63;

    floatx4 acc[MT][NT];
#pragma unroll
    for (int nt = 0; nt < NT; nt++) {
        float bv = (OUTMODE == 1) ? bias[nt * 16 + l16] : 0.f;
#pragma unroll
        for (int mt = 0; mt < MT; mt++) { floatx4 v = {bv, bv, bv, bv}; acc[mt][nt] = v; }
    }

    const int TOTAL = ntaps * NC;
    short8 Ah[2][MT], Al[2][MT], Bh[2][NT], Bl[2][NT];

    auto load_frag = [&](int slot, int it) {
        int tap = tap0 + it / NC;
        int ch = it % NC;
        int kh = tap / 3, kw = tap - kh * 3;
        // A: contiguous 1KB per instruction: pixel stride = 32 ushorts = 64B
        size_t r = ((size_t)((aC0 + ch) * 4 + b) * 4356 + (y + kh) * 66 + (x0 + kw) + l16) * 32 + quad * 8;
#pragma unroll
        for (int mt = 0; mt < MT; mt++) {
            Ah[slot][mt] = *(const short8*)(ah + r + (size_t)(mt * 16) * 32);
            Al[slot][mt] = *(const short8*)(al + r + (size_t)(mt * 16) * 32);
        }
        // B: contiguous 1KB per instruction: oc stride = 32 ushorts = 64B
        size_t wr = ((size_t)(ch * 9 + tap) * OCPAD + l16) * 32 + quad * 8;
#pragma unroll
        for (int nt = 0; nt < NT; nt++) {
            Bh[slot][nt] = *(const short8*)(wh + wr + (size_t)(nt * 16) * 32);
            Bl[slot][nt] = *(const short8*)(wl + wr + (size_t)(nt * 16) * 32);
        }
    };

    load_frag(0, 0);
#pragma unroll 2
    for (int it = 0; it < TOTAL; it++) {
        int cur = it & 1, nxt = cur ^ 1;
        if (it + 1 < TOTAL) load_frag(nxt, it + 1);
#pragma unroll
        for (int nt = 0; nt < NT; nt++) {
#pragma unroll
            for (int mt = 0; mt < MT; mt++) {
                acc[mt][nt] = __builtin_amdgcn_mfma_f32_16x16x32_bf16(Ah[cur][mt], Bh[cur][nt], acc[mt][nt], 0, 0, 0);
                acc[mt][nt] = __builtin_amdgcn_mfma_f32_16x16x32_bf16(Ah[cur][mt], Bl[cur][nt], acc[mt][nt], 0, 0, 0);
                acc[mt][nt] = __builtin_amdgcn_mfma_f32_16x16x32_bf16(Al[cur][mt], Bh[cur][nt], acc[mt][nt], 0, 0, 0);
            }
        }
    }

#pragma unroll
    for (int nt = 0; nt < NT; nt++) {
        int oc = nt * 16 + l16;
#pragma unroll
        for (int mt = 0; mt < MT; mt++) {
#pragma unroll
            for (int r = 0; r < 4; r++) {
                float v = acc[mt][nt][r];
                int px = pix0 + mt * 16 + quad * 4 + r;
                if (OUTMODE == 2) {
                    atomicAdd(pf + ((size_t)b * 4096 + px) * OCPAD + oc, v);
                } else if (OUTMODE == 3) {
                    pf[((size_t)b * 4096 + px) * orow + oc0 + oc] = v;
                } else {
                    if (ACT == 1) v = gelu_exact(v);
                    else if (ACT == 2) v = 1.0f / (1.0f + expf(-v));
                    int yy = (px >> 6) + 1, xx = (px & 63) + 1;
                    int och = oC0 + (oc >> 5);
                    size_t o = ((size_t)(och * 4 + b) * 4356 + yy * 66 + xx) * 32 + (oc & 31);
                    unsigned short hv, lv; split2(v, &hv, &lv);
                    oh[o] = hv; ol[o] = lv;
                }
            }
        }
    }
}

// convA (K-split x3): conv1 (grouped C->C -> P1 partials) fused with
// conv3 (256->64 -> P3 partials). grid.x = 480:
//  [0,384): conv1: ks=bx/128, g=(bx%128)>>5, mb=bx&31
//  [384,480): conv3: ks=(bx-384)>>5, mb=(bx-384)&31
__global__ __launch_bounds__(256, 2) void convA_kernel(
    const unsigned short* __restrict__ xph, const unsigned short* __restrict__ xpl,
    const unsigned short* __restrict__ w1h, const unsigned short* __restrict__ w1l,
    const unsigned short* __restrict__ w3h, const unsigned short* __restrict__ w3l,
    float* __restrict__ P1, float* __restrict__ P3)
{
    int b = blockIdx.z;
    int bx = blockIdx.x;
    if (bx < 384) {
        int ks = bx / 128;
        int rem = bx - ks * 128;
        int g = rem >> 5;
        int mb = rem & 31;
        conv_core<2, 2, 4, 0, 3>(xph, xpl, g * 2,
            w1h + (size_t)g * 2 * 9 * 64 * 32, w1l + (size_t)g * 2 * 9 * 64 * 32, nullptr,
            b, mb, ks * 3, 3, nullptr, nullptr, 0,
            P1 + (size_t)ks * 4 * 4096 * 256, 256, g * 64);
    } else {
        int t = bx - 384;
        int ks = t >> 5;
        int mb = t & 31;
        conv_core<8, 2, 4, 0, 3>(xph, xpl, 0, w3h, w3l, nullptr,
            b, mb, ks * 3, 3, nullptr, nullptr, 0,
            P3 + (size_t)ks * 4 * 4096 * 64, 64, 0);
    }
}

// finalizeA: h1 = gelu(sum P1 + b1) -> chunked split-bf16; same for m1 from P3.
__global__ __launch_bounds__(256) void finalizeA_kernel(
    const float* __restrict__ P1, const float* __restrict__ P3,
    const float* __restrict__ off_b1, const float* __restrict__ mod_b1,
    unsigned short* __restrict__ h1h, unsigned short* __restrict__ h1l,
    unsigned short* __restrict__ m1h, unsigned short* __restrict__ m1l)
{
    int p = blockIdx.x;            // b*4096 + px
    int b = p >> 12;
    int px = p & 4095;
    int rem = ((px >> 6) + 1) * 66 + (px & 63) + 1;
    int t = threadIdx.x;
    const size_t S1 = (size_t)4 * 4096 * 256;
    float v = P1[(size_t)p * 256 + t] + P1[S1 + (size_t)p * 256 + t]
            + P1[2 * S1 + (size_t)p * 256 + t] + off_b1[t];
    v = gelu_exact(v);
    size_t o = ((size_t)((t >> 5) * 4 + b) * 4356 + rem) * 32 + (t & 31);
    unsigned short hv, lv; split2(v, &hv, &lv);
    h1h[o] = hv; h1l[o] = lv;
    if (t < 64) {
        const size_t S3 = (size_t)4 * 4096 * 64;
        float u = P3[(size_t)p * 64 + t] + P3[S3 + (size_t)p * 64 + t]
                + P3[2 * S3 + (size_t)p * 64 + t] + mod_b1[t];
        u = gelu_exact(u);
        size_t o3 = ((size_t)((t >> 5) * 4 + b) * 4356 + rem) * 32 + (t & 31);
        unsigned short hu, lu; split2(u, &hu, &lu);
        m1h[o3] = hu; m1l[o3] = lu;
    }
}

// convB: conv2 (256->80pad, K-split x3 -> P2a atomics) fused with
//        conv4 (64->48pad, K-split x3 -> P4a atomics)
// grid.x = 192: [0,96) conv2 (ks=bx>>5, mb=bx&31), [96,192) conv4
__global__ __launch_bounds__(256, 2) void convB_kernel(
    const unsigned short* __restrict__ h1h, const unsigned short* __restrict__ h1l,
    const unsigned short* __restrict__ w2h, const unsigned short* __restrict__ w2l,
    const unsigned short* __restrict__ m1h, const unsigned short* __restrict__ m1l,
    const unsigned short* __restrict__ w4h, const unsigned short* __restrict__ w4l,
    float* __restrict__ P2a, float* __restrict__ P4a)
{
    int b = blockIdx.z;
    if (blockIdx.x < 96) {
        int ks = blockIdx.x >> 5;
        int mb = blockIdx.x & 31;
        conv_core<8, 2, 5, 0, 2>(h1h, h1l, 0, w2h, w2l, nullptr,
            b, mb, ks * 3, 3, nullptr, nullptr, 0, P2a, 0, 0);
    } else {
        int t = blockIdx.x - 96;
        int ks = t >> 5;
        int mb = t & 31;
        conv_core<2, 2, 3, 0, 2>(m1h, m1l, 0, w4h, w4l, nullptr,
            b, mb, ks * 3, 3, nullptr, nullptr, 0, P4a, 0, 0);
    }
}

// finalizeB: offo = P2a + b2 ; modo = sigmoid(P4a + b4)
__global__ __launch_bounds__(128) void finalizeB_kernel(
    const float* __restrict__ P2a, const float* __restrict__ P4a,
    const float* __restrict__ b2, const float* __restrict__ b4,
    float* __restrict__ offo, float* __restrict__ modo)
{
    size_t p = blockIdx.x;   // b*4096+hw
    int t = threadIdx.x;
    if (t < 80) {
        if (t < 72) offo[p * 72 + t] = P2a[p * 80 + t] + b2[t];
    } else {
        int u = t - 80;
        if (u < 36) {
            float v = P4a[p * 48 + u] + b4[u];
            modo[p * 36 + u] = 1.0f / (1.0f + expf(-v));
        }
    }
}

// ---------------- prep kernels ----------------
// x [B,HW,256] -> chunked padded split-bf16: xp[ch][b][4356][32]
__global__ void prep_x_kernel(const float* __restrict__ x,
                              unsigned short* __restrict__ xph, unsigned short* __restrict__ xpl)
{
    int bid = blockIdx.x;           // b*4356 + i*66 + j
    int c = threadIdx.x;
    int b = bid / 4356;
    int rem = bid - b * 4356;
    int i = rem / 66, j = rem - i * 66;
    float v = 0.f;
    if (i >= 1 && i <= 64 && j >= 1 && j <= 64)
        v = x[((size_t)b * 4096 + (size_t)(i - 1) * 64 + (j - 1)) * 256 + c];
    size_t o = ((size_t)((c >> 5) * 4 + b) * 4356 + rem) * 32 + (c & 31);
    unsigned short h, l; split2(v, &h, &l);
    xph[o] = h; xpl[o] = l;
}

// zero only the halo ring (260 px/image) of h1pad (8 chunks) and m1pad (2 chunks)
__global__ void ring_zero_kernel(unsigned short* __restrict__ h1h, unsigned short* __restrict__ h1l,
                                 unsigned short* __restrict__ m1h, unsigned short* __restrict__ m1l)
{
    int bid = blockIdx.x;           // b*260 + r
    int b = bid / 260;
    int r = bid - b * 260;
    int i, j;
    if (r < 66)       { i = 0;        j = r; }
    else if (r < 132) { i = 65;       j = r - 66; }
    else if (r < 196) { i = r - 131;  j = 0; }     // rows 1..64
    else              { i = r - 195;  j = 65; }
    size_t pp = (size_t)i * 66 + j;
    int t = threadIdx.x;
    int ch = t >> 5, sub = t & 31;
    size_t o = ((size_t)(ch * 4 + b) * 4356 + pp) * 32 + sub;
    h1h[o] = 0; h1l[o] = 0;
    if (t < 64) { m1h[o] = 0; m1l[o] = 0; }
}

__global__ void zerofill_kernel(uint4* __restrict__ p, int n)
{
    int i = blockIdx.x * 256 + threadIdx.x;
    if (i < n) p[i] = make_uint4(0u, 0u, 0u, 0u);
}

// merged weight prep. OIHW fp32 -> [g][ch][tap][OCPAD][32] split bf16 (zero-pad oc)
__global__ void prep_w_all_kernel(
    const float* __restrict__ w1, const float* __restrict__ w2,
    const float* __restrict__ w3, const float* __restrict__ w4,
    unsigned short* __restrict__ w1h, unsigned short* __restrict__ w1l,
    unsigned short* __restrict__ w2h, unsigned short* __restrict__ w2l,
    unsigned short* __restrict__ w3h, unsigned short* __restrict__ w3l,
    unsigned short* __restrict__ w4h, unsigned short* __restrict__ w4l)
{
    const int N1 = 147456, N2 = 184320, N3 = 147456, N4 = 27648;
    int idx = blockIdx.x * 256 + threadIdx.x;
    const float* w; unsigned short *outh, *outl;
    int ocpad, oc_real, ic, base;
    if (idx < N1)                { w = w1; outh = w1h; outl = w1l; ocpad = 64; oc_real = 64; ic = 64;  base = 0; }
    else if (idx < N1 + N2)      { w = w2; outh = w2h; outl = w2l; ocpad = 80; oc_real = 72; ic = 256; base = N1; }
    else if (idx < N1 + N2 + N3) { w = w3; outh = w3h; outl = w3l; ocpad = 64; oc_real = 64; ic = 256; base = N1 + N2; }
    else if (idx < N1 + N2 + N3 + N4) { w = w4; outh = w4h; outl = w4l; ocpad = 48; oc_real = 36; ic = 64; base = N1 + N2 + N3; }
    else return;
    int lidx = idx - base;
    // lidx -> [g][ch][tap][ocp][ici]
    int ici = lidx & 31;
    int t1 = lidx >> 5;
    int ocp = t1 % ocpad;
    int t2 = t1 / ocpad;
    int tap = t2 % 9;
    int t3 = t2 / 9;
    int nch = ic >> 5;
    int ch = t3 % nch;
    int g = t3 / nch;
    float v = 0.f;
    if (ocp < oc_real) {
        int oc = g * oc_real + ocp;
        int icx = ch * 32 + ici;
        v = w[((size_t)oc * ic + icx) * 9 + tap];
    }
    unsigned short h, l; split2(v, &h, &l);
    outh[lidx] = h; outl[lidx] = l;
}

// ---------------- deformable sampling (exact fp32) ----------------
__global__ __launch_bounds__(256) void deform_sample(
    const float* __restrict__ x, const float* __restrict__ off,
    const float* __restrict__ mod, float* __restrict__ out)
{
    const int W = 64;
    int wave = (int)((blockIdx.x * 256u + threadIdx.x) >> 6);
    int lane = (int)(threadIdx.x & 63u);

    int b  = wave >> 14;
    int g  = (wave >> 12) & 3;
    int hw = wave & 4095;
    int hy = hw >> 6;
    int wx = hw & 63;

    float fx = 0.f, fy = 0.f, fm = 0.f;
    int p = lane;
    if (lane < 9) {
        const float* ob = off + ((size_t)(b << 12) + hw) * 72 + g * 18;
        fx = ob[p];
        fy = ob[9 + p];
        fm = mod[((size_t)(b << 12) + hw) * 36 + g * 9 + p];
    }
    float px = fminf(fmaxf((float)wx + (float)(p % 3 - 1) + fx, 0.f), 63.f);
    float py = fminf(fmaxf((float)hy + (float)(p / 3 - 1) + fy, 0.f), 63.f);
    float x0f = floorf(px), y0f = floorf(py);
    float wxf = px - x0f, wyf = py - y0f;
    int x0 = (int)x0f, y0 = (int)y0f;
    int x1 = min(x0 + 1, 63), y1 = min(y0 + 1, 63);

    const float* xb = x + ((size_t)(b << 12)) * 256 + g * 64 + lane;
    float acc = 0.f;
#pragma unroll
    for (int q = 0; q < 9; q++) {
        int   qx0 = __shfl(x0, q);
        int   qx1 = __shfl(x1, q);
        int   qy0 = __shfl(y0, q);
        int   qy1 = __shfl(y1, q);
        float qwx = __shfl(wxf, q);
        float qwy = __shfl(wyf, q);
        float qm  = __shfl(fm, q);
        float v00 = xb[((size_t)(qy0 * W + qx0)) * 256];
        float v01 = xb[((size_t)(qy0 * W + qx1)) * 256];
        float v10 = xb[((size_t)(qy1 * W + qx0)) * 256];
        float v11 = xb[((size_t)(qy1 * W + qx1)) * 256];
        float vv = v00 * (1.f - qwx) * (1.f - qwy)
                 + v01 * qwx * (1.f - qwy)
                 + v10 * (1.f - qwx) * qwy
                 + v11 * qwx * qwy;
        acc += qm * vv;
    }
    out[((size_t)(b << 12) + hw) * 256 + g * 64 + lane] = acc * (1.f / 9.f);
}

extern "C" void kernel_launch(void* const* d_in, const int* in_sizes, int n_in,
                              void* d_out, int out_size, void* d_ws, size_t ws_size,
                              hipStream_t stream)
{
    const float* x      = (const float*)d_in[0];
    const float* off_w1 = (const float*)d_in[1];
    const float* off_b1 = (const float*)d_in[2];
    const float* off_w2 = (const float*)d_in[3];
    const float* off_b2 = (const float*)d_in[4];
    const float* mod_w1 = (const float*)d_in[5];
    const float* mod_b1 = (const float*)d_in[6];
    const float* mod_w2 = (const float*)d_in[7];
    const float* mod_b2 = (const float*)d_in[8];

    // ws layout (ushort units; all counts multiple of 8 -> 16B alignment holds)
    const size_t XP = 4u * 4356u * 256u;   // 4,460,544 (8 chunks x 4 b x 4356 x 32)
    const size_t MP = 4u * 4356u * 64u;    // 1,115,136 (2 chunks)
    const size_t W1 = 4u * 2u * 9u * 64u * 32u;  // 147,456
    const size_t W2 = 8u * 9u * 80u * 32u;       // 184,320
    const size_t W3 = 8u * 9u * 64u * 32u;       // 147,456
    const size_t W4 = 2u * 9u * 48u * 32u;       // 27,648

    unsigned short* ws = (unsigned short*)d_ws;
    size_t o = 0;
    unsigned short* xph = ws + o; o += XP;
    unsigned short* xpl = ws + o; o += XP;
    unsigned short* h1h = ws + o; o += XP;
    unsigned short* h1l = ws + o; o += XP;
    unsigned short* m1h = ws + o; o += MP;
    unsigned short* m1l = ws + o; o += MP;
    unsigned short* w1h = ws + o; o += W1;
    unsigned short* w1l = ws + o; o += W1;
    unsigned short* w2h = ws + o; o += W2;
    unsigned short* w2l = ws + o; o += W2;
    unsigned short* w3h = ws + o; o += W3;
    unsigned short* w3l = ws + o; o += W3;
    unsigned short* w4h = ws + o; o += W4;
    unsigned short* w4l = ws + o; o += W4;
    float* fbase = (float*)(ws + o);
    float* offo = fbase;                             // [4,4096,72]
    float* modo = offo + (size_t)4 * 4096 * 72;      // [4,4096,36]
    float* P1   = modo + (size_t)4 * 4096 * 36;      // 3 x [4,4096,256] partials
    float* P3   = P1 + (size_t)3 * 4 * 4096 * 256;   // 3 x [4,4096,64]  partials
    // K-split accumulators for convB ALIAS the xpad region (dead after convA):
    float* P2a = (float*)xph;                        // [4*4096][80]
    float* P4a = P2a + (size_t)4 * 4096 * 80;        // [4*4096][48]
    size_t need_floats = (size_t)4 * 4096 * (72 + 36) + (size_t)3 * 4 * 4096 * (256 + 64);
    size_t need_bytes = o * 2 + need_floats * 4;     // ~115 MB (ws is ~268 MB per poison fill)
    if (ws_size < need_bytes) return;  // deterministic guard

    ring_zero_kernel<<<4 * 260, 256, 0, stream>>>(h1h, h1l, m1h, m1l);
    prep_x_kernel<<<4 * 4356, 256, 0, stream>>>(x, xph, xpl);
    {
        const int NW = 147456 + 184320 + 147456 + 27648;
        prep_w_all_kernel<<<(NW + 255) / 256, 256, 0, stream>>>(
            off_w1, off_w2, mod_w1, mod_w2,
            w1h, w1l, w2h, w2l, w3h, w3l, w4h, w4l);
    }

    convA_kernel<<<dim3(480, 1, 4), 256, 0, stream>>>(xph, xpl, w1h, w1l, w3h, w3l, P1, P3);
    finalizeA_kernel<<<4 * 4096, 256, 0, stream>>>(P1, P3, off_b1, mod_b1,
                                                   h1h, h1l, m1h, m1l);
    // xpad now dead -> zero the aliased convB atomic accumulators
    zerofill_kernel<<<(2097152 / 4 + 255) / 256, 256, 0, stream>>>((uint4*)P2a, 2097152 / 4);
    convB_kernel<<<dim3(192, 1, 4), 256, 0, stream>>>(h1h, h1l, w2h, w2l,
                                                      m1h, m1l, w4h, w4l, P2a, P4a);
    finalizeB_kernel<<<4 * 4096, 128, 0, stream>>>(P2a, P4a, off_b2, mod_b2, offo, modo);
    deform_sample<<<16384, 256, 0, stream>>>(x, offo, modo, (float*)d_out);
}

// Round 7
// 254.091 us; speedup vs baseline: 2.0242x; 1.1780x over previous
//
#include <hip/hip_runtime.h>
#include <math.h>

// B=4, C=256, H=W=64, G=4, Cg=64, P=9. x [B,HW,C] is NHWC already.
// Convs via implicit-GEMM MFMA (bf16 2-term split: hi*hi + hi*lo + lo*hi).
// Chunked layout (R5): activations [ch][b][66*66 px][32ic], weights
// [ch][tap][OCPAD][32ic] -> every A/B fragment load is 1KB contiguous.
// R7: rebalanced split strategy per R6 counters (19% occupancy = conv3 tail):
//  - conv1: UN-split, direct bf16 output (512 blk x 18 it) - kills P1 traffic
//  - conv3: split x6 (3 tap-groups x 2 chunk-halves, 768 blk x 12 it)
//  - conv2: split x6 likewise (768 blk x 12 it, atomics)
//  - deform_sample: 4 points/wave, float4 gathers (4x fewer VMEM insts)

typedef __attribute__((ext_vector_type(8))) short short8;
typedef __attribute__((ext_vector_type(4))) float floatx4;

__device__ __forceinline__ unsigned short f2bf(float f) {
    unsigned u = __float_as_uint(f);
    u = (u + 0x7FFFu + ((u >> 16) & 1u)) >> 16;
    return (unsigned short)u;
}
__device__ __forceinline__ float bf2f(unsigned short h) {
    return __uint_as_float(((unsigned)h) << 16);
}
__device__ __forceinline__ void split2(float v, unsigned short* hi, unsigned short* lo) {
    unsigned short h = f2bf(v);
    *hi = h;
    *lo = f2bf(v - bf2f(h));
}
__device__ __forceinline__ float gelu_exact(float v) {
    return 0.5f * v * (1.0f + erff(v * 0.70710678118654752f));
}

// ---------------- MFMA implicit-GEMM conv core (chunked layout) ----------------
// Activations: [ch][b][4356 px][32] ushort (hi/lo arrays). px = y*66+x, padded.
// Weights (pre-offset for chunk/group base): [ch][tap][OCPAD][32] ushort.
// Wave tile: 32 px x NT*16 oc. Block = 4 waves = 128 consecutive px (2 rows).
// A frag: m=lane&15 -> pixel, k=quad*8+j -> ic. B frag: n=lane&15 -> oc.
// C/D: col(oc)=lane&15, row(pixel)=quad*4+reg.
// ACT: 0 none, 1 gelu(exact), 2 sigmoid.
// OUTMODE: 1 chunked split-bf16 out (bias+act), 2 fp32 atomicAdd partial,
//          3 fp32 plain write partial (row stride orow, col base oc0).
template<int NC, int MT, int NT, int ACT, int OUTMODE>
__device__ __forceinline__ void conv_core(
    const unsigned short* __restrict__ ah, const unsigned short* __restrict__ al,
    int aC0,
    const unsigned short* __restrict__ wh, const unsigned short* __restrict__ wl,
    const float* __restrict__ bias,
    int b, int mblock, int tap0, int ntaps,
    unsigned short* __restrict__ oh, unsigned short* __restrict__ ol,
    int oC0,
    float* __restrict__ pf, int orow, int oc0)
{
    const int OCPAD = NT * 16;
    int wave = threadIdx.x >> 6;
    int lane = threadIdx.x & 63;
    int quad = lane >> 4;
    int l16 = lane & 15;

    int pix0 = (mblock * 4 + wave) * (MT * 16);   // [0,4096)
    int y = pix0 >> 6;
    int x0 = pix0 & 63;

    floatx4 acc[MT][NT];
#pragma unroll
    for (int nt = 0; nt < NT; nt++) {
        float bv = (OUTMODE == 1) ? bias[nt * 16 + l16] : 0.f;
#pragma unroll
        for (int mt = 0; mt < MT; mt++) { floatx4 v = {bv, bv, bv, bv}; acc[mt][nt] = v; }
    }

    const int TOTAL = ntaps * NC;
    short8 Ah[2][MT], Al[2][MT], Bh[2][NT], Bl[2][NT];

    auto load_frag = [&](int slot, int it) {
        int tap = tap0 + it / NC;
        int ch = it % NC;
        int kh = tap / 3, kw = tap - kh * 3;
        // A: contiguous 1KB per instruction: pixel stride = 32 ushorts = 64B
        size_t r = ((size_t)((aC0 + ch) * 4 + b) * 4356 + (y + kh) * 66 + (x0 + kw) + l16) * 32 + quad * 8;
#pragma unroll
        for (int mt = 0; mt < MT; mt++) {
            Ah[slot][mt] = *(const short8*)(ah + r + (size_t)(mt * 16) * 32);
            Al[slot][mt] = *(const short8*)(al + r + (size_t)(mt * 16) * 32);
        }
        // B: contiguous 1KB per instruction: oc stride = 32 ushorts = 64B
        size_t wr = ((size_t)(ch * 9 + tap) * OCPAD + l16) * 32 + quad * 8;
#pragma unroll
        for (int nt = 0; nt < NT; nt++) {
            Bh[slot][nt] = *(const short8*)(wh + wr + (size_t)(nt * 16) * 32);
            Bl[slot][nt] = *(const short8*)(wl + wr + (size_t)(nt * 16) * 32);
        }
    };

    load_frag(0, 0);
#pragma unroll 2
    for (int it = 0; it < TOTAL; it++) {
        int cur = it & 1, nxt = cur ^ 1;
        if (it + 1 < TOTAL) load_frag(nxt, it + 1);
#pragma unroll
        for (int nt = 0; nt < NT; nt++) {
#pragma unroll
            for (int mt = 0; mt < MT; mt++) {
                acc[mt][nt] = __builtin_amdgcn_mfma_f32_16x16x32_bf16(Ah[cur][mt], Bh[cur][nt], acc[mt][nt], 0, 0, 0);
                acc[mt][nt] = __builtin_amdgcn_mfma_f32_16x16x32_bf16(Ah[cur][mt], Bl[cur][nt], acc[mt][nt], 0, 0, 0);
                acc[mt][nt] = __builtin_amdgcn_mfma_f32_16x16x32_bf16(Al[cur][mt], Bh[cur][nt], acc[mt][nt], 0, 0, 0);
            }
        }
    }

#pragma unroll
    for (int nt = 0; nt < NT; nt++) {
        int oc = nt * 16 + l16;
#pragma unroll
        for (int mt = 0; mt < MT; mt++) {
#pragma unroll
            for (int r = 0; r < 4; r++) {
                float v = acc[mt][nt][r];
                int px = pix0 + mt * 16 + quad * 4 + r;
                if (OUTMODE == 2) {
                    atomicAdd(pf + ((size_t)b * 4096 + px) * OCPAD + oc, v);
                } else if (OUTMODE == 3) {
                    pf[((size_t)b * 4096 + px) * orow + oc0 + oc] = v;
                } else {
                    if (ACT == 1) v = gelu_exact(v);
                    else if (ACT == 2) v = 1.0f / (1.0f + expf(-v));
                    int yy = (px >> 6) + 1, xx = (px & 63) + 1;
                    int och = oC0 + (oc >> 5);
                    size_t o = ((size_t)(och * 4 + b) * 4356 + yy * 66 + xx) * 32 + (oc & 31);
                    unsigned short hv, lv; split2(v, &hv, &lv);
                    oh[o] = hv; ol[o] = lv;
                }
            }
        }
    }
}

// convA: conv1 (grouped C->C, gelu, direct ->h1pad) + conv3 (256->64, K-split x6 -> P3)
// grid.x = 320: [0,128): conv1 long blocks first (g=bx>>5, mb=bx&31, 18 iters)
//               [128,320): conv3: ks=(bx-128)>>5 in [0,6), mb=&31, 12 iters
__global__ __launch_bounds__(256, 2) void convA_kernel(
    const unsigned short* __restrict__ xph, const unsigned short* __restrict__ xpl,
    const unsigned short* __restrict__ w1h, const unsigned short* __restrict__ w1l,
    const float* __restrict__ off_b1,
    const unsigned short* __restrict__ w3h, const unsigned short* __restrict__ w3l,
    unsigned short* __restrict__ h1h, unsigned short* __restrict__ h1l,
    float* __restrict__ P3)
{
    int b = blockIdx.z;
    int bx = blockIdx.x;
    if (bx < 128) {
        int g = bx >> 5;
        int mb = bx & 31;
        conv_core<2, 2, 4, 1, 1>(xph, xpl, g * 2,
            w1h + (size_t)g * 2 * 9 * 64 * 32, w1l + (size_t)g * 2 * 9 * 64 * 32,
            off_b1 + g * 64,
            b, mb, 0, 9, h1h, h1l, g * 2, nullptr, 0, 0);
    } else {
        int t = bx - 128;
        int ks = t >> 5;           // 0..5
        int mb = t & 31;
        int ks_c = ks & 1;         // chunk half: chunks 0-3 / 4-7
        int ks_t = ks >> 1;        // tap group: 0..2
        conv_core<4, 2, 4, 0, 3>(xph, xpl, ks_c * 4,
            w3h + (size_t)(ks_c * 4) * 9 * 64 * 32, w3l + (size_t)(ks_c * 4) * 9 * 64 * 32,
            nullptr,
            b, mb, ks_t * 3, 3, nullptr, nullptr, 0,
            P3 + (size_t)ks * 4 * 4096 * 64, 64, 0);
    }
}

// finalizeA: m1 = gelu(sum of 6 P3 slices + mod_b1) -> chunked split-bf16.
__global__ __launch_bounds__(256) void finalizeA_kernel(
    const float* __restrict__ P3, const float* __restrict__ mod_b1,
    unsigned short* __restrict__ m1h, unsigned short* __restrict__ m1l)
{
    int idx = blockIdx.x * 256 + threadIdx.x;   // (b*4096+px)*64 + c
    int c = idx & 63;
    int p = idx >> 6;            // b*4096+px
    int b = p >> 12;
    int px = p & 4095;
    int rem = ((px >> 6) + 1) * 66 + (px & 63) + 1;
    const size_t S = (size_t)4 * 4096 * 64;
    const float* q = P3 + (size_t)p * 64 + c;
    float u = q[0] + q[S] + q[2 * S] + q[3 * S] + q[4 * S] + q[5 * S] + mod_b1[c];
    u = gelu_exact(u);
    size_t o = ((size_t)((c >> 5) * 4 + b) * 4356 + rem) * 32 + (c & 31);
    unsigned short hu, lu; split2(u, &hu, &lu);
    m1h[o] = hu; m1l[o] = lu;
}

// convB: conv2 (256->80pad, K-split x6 -> P2a atomics) + conv4 (64->48pad, x3 -> P4a)
// grid.x = 288: [0,192): conv2 (ks=bx>>5 in [0,6), mb=bx&31)
//               [192,288): conv4 (ks=(bx-192)>>5 in [0,3), mb=&31)
__global__ __launch_bounds__(256, 2) void convB_kernel(
    const unsigned short* __restrict__ h1h, const unsigned short* __restrict__ h1l,
    const unsigned short* __restrict__ w2h, const unsigned short* __restrict__ w2l,
    const unsigned short* __restrict__ m1h, const unsigned short* __restrict__ m1l,
    const unsigned short* __restrict__ w4h, const unsigned short* __restrict__ w4l,
    float* __restrict__ P2a, float* __restrict__ P4a)
{
    int b = blockIdx.z;
    int bx = blockIdx.x;
    if (bx < 192) {
        int ks = bx >> 5;          // 0..5
        int mb = bx & 31;
        int ks_c = ks & 1;
        int ks_t = ks >> 1;
        conv_core<4, 2, 5, 0, 2>(h1h, h1l, ks_c * 4,
            w2h + (size_t)(ks_c * 4) * 9 * 80 * 32, w2l + (size_t)(ks_c * 4) * 9 * 80 * 32,
            nullptr,
            b, mb, ks_t * 3, 3, nullptr, nullptr, 0, P2a, 0, 0);
    } else {
        int t = bx - 192;
        int ks = t >> 5;           // 0..2
        int mb = t & 31;
        conv_core<2, 2, 3, 0, 2>(m1h, m1l, 0, w4h, w4l, nullptr,
            b, mb, ks * 3, 3, nullptr, nullptr, 0, P4a, 0, 0);
    }
}

// finalizeB: offo = P2a + b2 ; modo = sigmoid(P4a + b4)
__global__ __launch_bounds__(128) void finalizeB_kernel(
    const float* __restrict__ P2a, const float* __restrict__ P4a,
    const float* __restrict__ b2, const float* __restrict__ b4,
    float* __restrict__ offo, float* __restrict__ modo)
{
    size_t p = blockIdx.x;   // b*4096+hw
    int t = threadIdx.x;
    if (t < 80) {
        if (t < 72) offo[p * 72 + t] = P2a[p * 80 + t] + b2[t];
    } else {
        int u = t - 80;
        if (u < 36) {
            float v = P4a[p * 48 + u] + b4[u];
            modo[p * 36 + u] = 1.0f / (1.0f + expf(-v));
        }
    }
}

// ---------------- prep kernels ----------------
// x [B,HW,256] -> chunked padded split-bf16: xp[ch][b][4356][32]
__global__ void prep_x_kernel(const float* __restrict__ x,
                              unsigned short* __restrict__ xph, unsigned short* __restrict__ xpl)
{
    int bid = blockIdx.x;           // b*4356 + i*66 + j
    int c = threadIdx.x;
    int b = bid / 4356;
    int rem = bid - b * 4356;
    int i = rem / 66, j = rem - i * 66;
    float v = 0.f;
    if (i >= 1 && i <= 64 && j >= 1 && j <= 64)
        v = x[((size_t)b * 4096 + (size_t)(i - 1) * 64 + (j - 1)) * 256 + c];
    size_t o = ((size_t)((c >> 5) * 4 + b) * 4356 + rem) * 32 + (c & 31);
    unsigned short h, l; split2(v, &h, &l);
    xph[o] = h; xpl[o] = l;
}

// zero only the halo ring (260 px/image) of h1pad (8 chunks) and m1pad (2 chunks)
__global__ void ring_zero_kernel(unsigned short* __restrict__ h1h, unsigned short* __restrict__ h1l,
                                 unsigned short* __restrict__ m1h, unsigned short* __restrict__ m1l)
{
    int bid = blockIdx.x;           // b*260 + r
    int b = bid / 260;
    int r = bid - b * 260;
    int i, j;
    if (r < 66)       { i = 0;        j = r; }
    else if (r < 132) { i = 65;       j = r - 66; }
    else if (r < 196) { i = r - 131;  j = 0; }     // rows 1..64
    else              { i = r - 195;  j = 65; }
    size_t pp = (size_t)i * 66 + j;
    int t = threadIdx.x;
    int ch = t >> 5, sub = t & 31;
    size_t o = ((size_t)(ch * 4 + b) * 4356 + pp) * 32 + sub;
    h1h[o] = 0; h1l[o] = 0;
    if (t < 64) { m1h[o] = 0; m1l[o] = 0; }
}

__global__ void zerofill_kernel(uint4* __restrict__ p, int n)
{
    int i = blockIdx.x * 256 + threadIdx.x;
    if (i < n) p[i] = make_uint4(0u, 0u, 0u, 0u);
}

// merged weight prep. OIHW fp32 -> [g][ch][tap][OCPAD][32] split bf16 (zero-pad oc)
__global__ void prep_w_all_kernel(
    const float* __restrict__ w1, const float* __restrict__ w2,
    const float* __restrict__ w3, const float* __restrict__ w4,
    unsigned short* __restrict__ w1h, unsigned short* __restrict__ w1l,
    unsigned short* __restrict__ w2h, unsigned short* __restrict__ w2l,
    unsigned short* __restrict__ w3h, unsigned short* __restrict__ w3l,
    unsigned short* __restrict__ w4h, unsigned short* __restrict__ w4l)
{
    const int N1 = 147456, N2 = 184320, N3 = 147456, N4 = 27648;
    int idx = blockIdx.x * 256 + threadIdx.x;
    const float* w; unsigned short *outh, *outl;
    int ocpad, oc_real, ic, base;
    if (idx < N1)                { w = w1; outh = w1h; outl = w1l; ocpad = 64; oc_real = 64; ic = 64;  base = 0; }
    else if (idx < N1 + N2)      { w = w2; outh = w2h; outl = w2l; ocpad = 80; oc_real = 72; ic = 256; base = N1; }
    else if (idx < N1 + N2 + N3) { w = w3; outh = w3h; outl = w3l; ocpad = 64; oc_real = 64; ic = 256; base = N1 + N2; }
    else if (idx < N1 + N2 + N3 + N4) { w = w4; outh = w4h; outl = w4l; ocpad = 48; oc_real = 36; ic = 64; base = N1 + N2 + N3; }
    else return;
    int lidx = idx - base;
    // lidx -> [g][ch][tap][ocp][ici]
    int ici = lidx & 31;
    int t1 = lidx >> 5;
    int ocp = t1 % ocpad;
    int t2 = t1 / ocpad;
    int tap = t2 % 9;
    int t3 = t2 / 9;
    int nch = ic >> 5;
    int ch = t3 % nch;
    int g = t3 / nch;
    float v = 0.f;
    if (ocp < oc_real) {
        int oc = g * oc_real + ocp;
        int icx = ch * 32 + ici;
        v = w[((size_t)oc * ic + icx) * 9 + tap];
    }
    unsigned short h, l; split2(v, &h, &l);
    outh[lidx] = h; outl[lidx] = l;
}

// ---------------- deformable sampling (exact fp32) ----------------
// 4 points per wave, 16 lanes per point, float4 gathers (4 channels/lane).
__global__ __launch_bounds__(256) void deform_sample(
    const float* __restrict__ x, const float* __restrict__ off,
    const float* __restrict__ mod, float* __restrict__ out)
{
    int wid = (int)((blockIdx.x * 256u + threadIdx.x) >> 6);   // 0..16383
    int lane = (int)(threadIdx.x & 63u);
    int sub = lane >> 4;         // 0..3: which point
    int li = lane & 15;

    int b = wid >> 12;           // 4096 waves per batch
    int rem = wid & 4095;
    int g = rem >> 10;
    int hw = ((rem & 1023) << 2) + sub;
    int hy = hw >> 6;
    int wx = hw & 63;

    // lanes li<9 of each subwave load offsets/mod for their point, p=li
    float fx = 0.f, fy = 0.f, fm = 0.f;
    if (li < 9) {
        const float* ob = off + ((size_t)(b << 12) + hw) * 72 + g * 18;
        fx = ob[li];
        fy = ob[9 + li];
        fm = mod[((size_t)(b << 12) + hw) * 36 + g * 9 + li];
    }
    float px = fminf(fmaxf((float)wx + (float)(li % 3 - 1) + fx, 0.f), 63.f);
    float py = fminf(fmaxf((float)hy + (float)(li / 3 - 1) + fy, 0.f), 63.f);
    float x0f = floorf(px), y0f = floorf(py);
    float wxf = px - x0f, wyf = py - y0f;
    int x0 = (int)x0f, y0 = (int)y0f;
    int x1 = min(x0 + 1, 63), y1 = min(y0 + 1, 63);

    // lane li gathers channels g*64 + li*4 .. +3 as float4
    const float4* xb = (const float4*)(x + ((size_t)(b << 12)) * 256 + g * 64 + li * 4);
    float4 acc = make_float4(0.f, 0.f, 0.f, 0.f);
    int sb = sub << 4;
#pragma unroll
    for (int q = 0; q < 9; q++) {
        int src = sb + q;
        int   qx0 = __shfl(x0, src);
        int   qx1 = __shfl(x1, src);
        int   qy0 = __shfl(y0, src);
        int   qy1 = __shfl(y1, src);
        float qwx = __shfl(wxf, src);
        float qwy = __shfl(wyf, src);
        float qm  = __shfl(fm, src);
        float4 v00 = xb[(size_t)(qy0 * 64 + qx0) * 64];
        float4 v01 = xb[(size_t)(qy0 * 64 + qx1) * 64];
        float4 v10 = xb[(size_t)(qy1 * 64 + qx0) * 64];
        float4 v11 = xb[(size_t)(qy1 * 64 + qx1) * 64];
        float w00 = (1.f - qwx) * (1.f - qwy);
        float w01 = qwx * (1.f - qwy);
        float w10 = (1.f - qwx) * qwy;
        float w11 = qwx * qwy;
        acc.x += qm * (v00.x * w00 + v01.x * w01 + v10.x * w10 + v11.x * w11);
        acc.y += qm * (v00.y * w00 + v01.y * w01 + v10.y * w10 + v11.y * w11);
        acc.z += qm * (v00.z * w00 + v01.z * w01 + v10.z * w10 + v11.z * w11);
        acc.w += qm * (v00.w * w00 + v01.w * w01 + v10.w * w10 + v11.w * w11);
    }
    const float s = 1.f / 9.f;
    acc.x *= s; acc.y *= s; acc.z *= s; acc.w *= s;
    float4* ob = (float4*)(out + ((size_t)(b << 12) + hw) * 256 + g * 64 + li * 4);
    *ob = acc;
}

extern "C" void kernel_launch(void* const* d_in, const int* in_sizes, int n_in,
                              void* d_out, int out_size, void* d_ws, size_t ws_size,
                              hipStream_t stream)
{
    const float* x      = (const float*)d_in[0];
    const float* off_w1 = (const float*)d_in[1];
    const float* off_b1 = (const float*)d_in[2];
    const float* off_w2 = (const float*)d_in[3];
    const float* off_b2 = (const float*)d_in[4];
    const float* mod_w1 = (const float*)d_in[5];
    const float* mod_b1 = (const float*)d_in[6];
    const float* mod_w2 = (const float*)d_in[7];
    const float* mod_b2 = (const float*)d_in[8];

    // ws layout (ushort units; all counts multiple of 8 -> 16B alignment holds)
    const size_t XP = 4u * 4356u * 256u;   // 4,460,544 (8 chunks x 4 b x 4356 x 32)
    const size_t MP = 4u * 4356u * 64u;    // 1,115,136 (2 chunks)
    const size_t W1 = 4u * 2u * 9u * 64u * 32u;  // 147,456
    const size_t W2 = 8u * 9u * 80u * 32u;       // 184,320
    const size_t W3 = 8u * 9u * 64u * 32u;       // 147,456
    const size_t W4 = 2u * 9u * 48u * 32u;       // 27,648

    unsigned short* ws = (unsigned short*)d_ws;
    size_t o = 0;
    unsigned short* xph = ws + o; o += XP;
    unsigned short* xpl = ws + o; o += XP;
    unsigned short* h1h = ws + o; o += XP;
    unsigned short* h1l = ws + o; o += XP;
    unsigned short* m1h = ws + o; o += MP;
    unsigned short* m1l = ws + o; o += MP;
    unsigned short* w1h = ws + o; o += W1;
    unsigned short* w1l = ws + o; o += W1;
    unsigned short* w2h = ws + o; o += W2;
    unsigned short* w2l = ws + o; o += W2;
    unsigned short* w3h = ws + o; o += W3;
    unsigned short* w3l = ws + o; o += W3;
    unsigned short* w4h = ws + o; o += W4;
    unsigned short* w4l = ws + o; o += W4;
    float* fbase = (float*)(ws + o);
    float* offo = fbase;                             // [4,4096,72]
    float* modo = offo + (size_t)4 * 4096 * 72;      // [4,4096,36]
    float* P3   = modo + (size_t)4 * 4096 * 36;      // 6 x [4,4096,64] partials
    // K-split accumulators for convB ALIAS the xpad region (dead after convA):
    float* P2a = (float*)xph;                        // [4*4096][80]
    float* P4a = P2a + (size_t)4 * 4096 * 80;        // [4*4096][48]
    size_t need_floats = (size_t)4 * 4096 * (72 + 36) + (size_t)6 * 4 * 4096 * 64;
    size_t need_bytes = o * 2 + need_floats * 4;     // ~64 MB (ws ~268 MB)
    if (ws_size < need_bytes) return;  // deterministic guard

    ring_zero_kernel<<<4 * 260, 256, 0, stream>>>(h1h, h1l, m1h, m1l);
    prep_x_kernel<<<4 * 4356, 256, 0, stream>>>(x, xph, xpl);
    {
        const int NW = 147456 + 184320 + 147456 + 27648;
        prep_w_all_kernel<<<(NW + 255) / 256, 256, 0, stream>>>(
            off_w1, off_w2, mod_w1, mod_w2,
            w1h, w1l, w2h, w2l, w3h, w3l, w4h, w4l);
    }

    convA_kernel<<<dim3(320, 1, 4), 256, 0, stream>>>(xph, xpl, w1h, w1l, off_b1,
                                                      w3h, w3l, h1h, h1l, P3);
    finalizeA_kernel<<<4096, 256, 0, stream>>>(P3, mod_b1, m1h, m1l);
    // xpad now dead -> zero the aliased convB atomic accumulators
    zerofill_kernel<<<(2097152 / 4 + 255) / 256, 256, 0, stream>>>((uint4*)P2a, 2097152 / 4);
    convB_kernel<<<dim3(288, 1, 4), 256, 0, stream>>>(h1h, h1l, w2h, w2l,
                                                      m1h, m1l, w4h, w4l, P2a, P4a);
    finalizeB_kernel<<<4 * 4096, 128, 0, stream>>>(P2a, P4a, off_b2, mod_b2, offo, modo);
    deform_sample<<<4096, 256, 0, stream>>>(x, offo, modo, (float*)d_out);
}

// Round 8
// 247.056 us; speedup vs baseline: 2.0818x; 1.0285x over previous
//
#include <hip/hip_runtime.h>
#include <math.h>

// B=4, C=256, H=W=64, G=4, Cg=64, P=9. x [B,HW,C] is NHWC already.
// Convs via implicit-GEMM MFMA (bf16 2-term split: hi*hi + hi*lo + lo*hi).
// Chunked layout (R5): activations [ch][b][66*66 px][32ic], weights
// [ch][tap][OCPAD][32ic] -> every A/B fragment load is 1KB contiguous.
// R8 (per R7 counters: convA dur == HBM bytes / 1.03 TB/s; P3 round-trip was
// 50 MB of the 71): conv3 K-split x6 now atomicAdds into ONE 4.2 MB P3
// buffer; all accumulators zeroed in one up-front dispatch; finalizeB fused
// into deform_sample (offo/modo never materialized).

typedef __attribute__((ext_vector_type(8))) short short8;
typedef __attribute__((ext_vector_type(4))) float floatx4;

__device__ __forceinline__ unsigned short f2bf(float f) {
    unsigned u = __float_as_uint(f);
    u = (u + 0x7FFFu + ((u >> 16) & 1u)) >> 16;
    return (unsigned short)u;
}
__device__ __forceinline__ float bf2f(unsigned short h) {
    return __uint_as_float(((unsigned)h) << 16);
}
__device__ __forceinline__ void split2(float v, unsigned short* hi, unsigned short* lo) {
    unsigned short h = f2bf(v);
    *hi = h;
    *lo = f2bf(v - bf2f(h));
}
__device__ __forceinline__ float gelu_exact(float v) {
    return 0.5f * v * (1.0f + erff(v * 0.70710678118654752f));
}

// ---------------- MFMA implicit-GEMM conv core (chunked layout) ----------------
// Activations: [ch][b][4356 px][32] ushort (hi/lo arrays). px = y*66+x, padded.
// Weights (pre-offset for chunk/group base): [ch][tap][OCPAD][32] ushort.
// Wave tile: 32 px x NT*16 oc. Block = 4 waves = 128 consecutive px (2 rows).
// A frag: m=lane&15 -> pixel, k=quad*8+j -> ic. B frag: n=lane&15 -> oc.
// C/D: col(oc)=lane&15, row(pixel)=quad*4+reg.
// ACT: 0 none, 1 gelu(exact), 2 sigmoid.
// OUTMODE: 1 chunked split-bf16 out (bias+act), 2 fp32 atomicAdd partial.
template<int NC, int MT, int NT, int ACT, int OUTMODE>
__device__ __forceinline__ void conv_core(
    const unsigned short* __restrict__ ah, const unsigned short* __restrict__ al,
    int aC0,
    const unsigned short* __restrict__ wh, const unsigned short* __restrict__ wl,
    const float* __restrict__ bias,
    int b, int mblock, int tap0, int ntaps,
    unsigned short* __restrict__ oh, unsigned short* __restrict__ ol,
    int oC0,
    float* __restrict__ pf)
{
    const int OCPAD = NT * 16;
    int wave = threadIdx.x >> 6;
    int lane = threadIdx.x & 63;
    int quad = lane >> 4;
    int l16 = lane & 15;

    int pix0 = (mblock * 4 + wave) * (MT * 16);   // [0,4096)
    int y = pix0 >> 6;
    int x0 = pix0 & 63;

    floatx4 acc[MT][NT];
#pragma unroll
    for (int nt = 0; nt < NT; nt++) {
        float bv = (OUTMODE == 1) ? bias[nt * 16 + l16] : 0.f;
#pragma unroll
        for (int mt = 0; mt < MT; mt++) { floatx4 v = {bv, bv, bv, bv}; acc[mt][nt] = v; }
    }

    const int TOTAL = ntaps * NC;
    short8 Ah[2][MT], Al[2][MT], Bh[2][NT], Bl[2][NT];

    auto load_frag = [&](int slot, int it) {
        int tap = tap0 + it / NC;
        int ch = it % NC;
        int kh = tap / 3, kw = tap - kh * 3;
        // A: contiguous 1KB per instruction: pixel stride = 32 ushorts = 64B
        size_t r = ((size_t)((aC0 + ch) * 4 + b) * 4356 + (y + kh) * 66 + (x0 + kw) + l16) * 32 + quad * 8;
#pragma unroll
        for (int mt = 0; mt < MT; mt++) {
            Ah[slot][mt] = *(const short8*)(ah + r + (size_t)(mt * 16) * 32);
            Al[slot][mt] = *(const short8*)(al + r + (size_t)(mt * 16) * 32);
        }
        // B: contiguous 1KB per instruction: oc stride = 32 ushorts = 64B
        size_t wr = ((size_t)(ch * 9 + tap) * OCPAD + l16) * 32 + quad * 8;
#pragma unroll
        for (int nt = 0; nt < NT; nt++) {
            Bh[slot][nt] = *(const short8*)(wh + wr + (size_t)(nt * 16) * 32);
            Bl[slot][nt] = *(const short8*)(wl + wr + (size_t)(nt * 16) * 32);
        }
    };

    load_frag(0, 0);
#pragma unroll 2
    for (int it = 0; it < TOTAL; it++) {
        int cur = it & 1, nxt = cur ^ 1;
        if (it + 1 < TOTAL) load_frag(nxt, it + 1);
#pragma unroll
        for (int nt = 0; nt < NT; nt++) {
#pragma unroll
            for (int mt = 0; mt < MT; mt++) {
                acc[mt][nt] = __builtin_amdgcn_mfma_f32_16x16x32_bf16(Ah[cur][mt], Bh[cur][nt], acc[mt][nt], 0, 0, 0);
                acc[mt][nt] = __builtin_amdgcn_mfma_f32_16x16x32_bf16(Ah[cur][mt], Bl[cur][nt], acc[mt][nt], 0, 0, 0);
                acc[mt][nt] = __builtin_amdgcn_mfma_f32_16x16x32_bf16(Al[cur][mt], Bh[cur][nt], acc[mt][nt], 0, 0, 0);
            }
        }
    }

#pragma unroll
    for (int nt = 0; nt < NT; nt++) {
        int oc = nt * 16 + l16;
#pragma unroll
        for (int mt = 0; mt < MT; mt++) {
#pragma unroll
            for (int r = 0; r < 4; r++) {
                float v = acc[mt][nt][r];
                int px = pix0 + mt * 16 + quad * 4 + r;
                if (OUTMODE == 2) {
                    atomicAdd(pf + ((size_t)b * 4096 + px) * OCPAD + oc, v);
                } else {
                    if (ACT == 1) v = gelu_exact(v);
                    else if (ACT == 2) v = 1.0f / (1.0f + expf(-v));
                    int yy = (px >> 6) + 1, xx = (px & 63) + 1;
                    int och = oC0 + (oc >> 5);
                    size_t o = ((size_t)(och * 4 + b) * 4356 + yy * 66 + xx) * 32 + (oc & 31);
                    unsigned short hv, lv; split2(v, &hv, &lv);
                    oh[o] = hv; ol[o] = lv;
                }
            }
        }
    }
}

// convA: conv1 (grouped C->C, gelu, direct ->h1pad) + conv3 (256->64, K-split x6 -> P3 atomics)
// grid.x = 320: [0,128): conv1 long blocks first (g=bx>>5, mb=bx&31, 18 iters)
//               [128,320): conv3: ks=(bx-128)>>5 in [0,6), mb=&31, 12 iters
__global__ __launch_bounds__(256, 2) void convA_kernel(
    const unsigned short* __restrict__ xph, const unsigned short* __restrict__ xpl,
    const unsigned short* __restrict__ w1h, const unsigned short* __restrict__ w1l,
    const float* __restrict__ off_b1,
    const unsigned short* __restrict__ w3h, const unsigned short* __restrict__ w3l,
    unsigned short* __restrict__ h1h, unsigned short* __restrict__ h1l,
    float* __restrict__ P3)
{
    int b = blockIdx.z;
    int bx = blockIdx.x;
    if (bx < 128) {
        int g = bx >> 5;
        int mb = bx & 31;
        conv_core<2, 2, 4, 1, 1>(xph, xpl, g * 2,
            w1h + (size_t)g * 2 * 9 * 64 * 32, w1l + (size_t)g * 2 * 9 * 64 * 32,
            off_b1 + g * 64,
            b, mb, 0, 9, h1h, h1l, g * 2, nullptr);
    } else {
        int t = bx - 128;
        int ks = t >> 5;           // 0..5
        int mb = t & 31;
        int ks_c = ks & 1;         // chunk half: chunks 0-3 / 4-7
        int ks_t = ks >> 1;        // tap group: 0..2
        conv_core<4, 2, 4, 0, 2>(xph, xpl, ks_c * 4,
            w3h + (size_t)(ks_c * 4) * 9 * 64 * 32, w3l + (size_t)(ks_c * 4) * 9 * 64 * 32,
            nullptr,
            b, mb, ks_t * 3, 3, nullptr, nullptr, 0, P3);
    }
}

// finalizeA: m1 = gelu(P3 + mod_b1) -> chunked split-bf16.
__global__ __launch_bounds__(256) void finalizeA_kernel(
    const float* __restrict__ P3, const float* __restrict__ mod_b1,
    unsigned short* __restrict__ m1h, unsigned short* __restrict__ m1l)
{
    int idx = blockIdx.x * 256 + threadIdx.x;   // (b*4096+px)*64 + c
    int c = idx & 63;
    int p = idx >> 6;            // b*4096+px
    int b = p >> 12;
    int px = p & 4095;
    int rem = ((px >> 6) + 1) * 66 + (px & 63) + 1;
    float u = P3[(size_t)p * 64 + c] + mod_b1[c];
    u = gelu_exact(u);
    size_t o = ((size_t)((c >> 5) * 4 + b) * 4356 + rem) * 32 + (c & 31);
    unsigned short hu, lu; split2(u, &hu, &lu);
    m1h[o] = hu; m1l[o] = lu;
}

// convB: conv2 (256->80pad, K-split x6 -> P2a atomics) + conv4 (64->48pad, x3 -> P4a)
// grid.x = 288: [0,192): conv2 (ks=bx>>5 in [0,6), mb=bx&31)
//               [192,288): conv4 (ks=(bx-192)>>5 in [0,3), mb=&31)
__global__ __launch_bounds__(256, 2) void convB_kernel(
    const unsigned short* __restrict__ h1h, const unsigned short* __restrict__ h1l,
    const unsigned short* __restrict__ w2h, const unsigned short* __restrict__ w2l,
    const unsigned short* __restrict__ m1h, const unsigned short* __restrict__ m1l,
    const unsigned short* __restrict__ w4h, const unsigned short* __restrict__ w4l,
    float* __restrict__ P2a, float* __restrict__ P4a)
{
    int b = blockIdx.z;
    int bx = blockIdx.x;
    if (bx < 192) {
        int ks = bx >> 5;          // 0..5
        int mb = bx & 31;
        int ks_c = ks & 1;
        int ks_t = ks >> 1;
        conv_core<4, 2, 5, 0, 2>(h1h, h1l, ks_c * 4,
            w2h + (size_t)(ks_c * 4) * 9 * 80 * 32, w2l + (size_t)(ks_c * 4) * 9 * 80 * 32,
            nullptr,
            b, mb, ks_t * 3, 3, nullptr, nullptr, 0, P2a);
    } else {
        int t = bx - 192;
        int ks = t >> 5;           // 0..2
        int mb = t & 31;
        conv_core<2, 2, 3, 0, 2>(m1h, m1l, 0, w4h, w4l, nullptr,
            b, mb, ks * 3, 3, nullptr, nullptr, 0, P4a);
    }
}

// ---------------- prep kernels ----------------
// x [B,HW,256] -> chunked padded split-bf16: xp[ch][b][4356][32]
__global__ void prep_x_kernel(const float* __restrict__ x,
                              unsigned short* __restrict__ xph, unsigned short* __restrict__ xpl)
{
    int bid = blockIdx.x;           // b*4356 + i*66 + j
    int c = threadIdx.x;
    int b = bid / 4356;
    int rem = bid - b * 4356;
    int i = rem / 66, j = rem - i * 66;
    float v = 0.f;
    if (i >= 1 && i <= 64 && j >= 1 && j <= 64)
        v = x[((size_t)b * 4096 + (size_t)(i - 1) * 64 + (j - 1)) * 256 + c];
    size_t o = ((size_t)((c >> 5) * 4 + b) * 4356 + rem) * 32 + (c & 31);
    unsigned short h, l; split2(v, &h, &l);
    xph[o] = h; xpl[o] = l;
}

// zero only the halo ring (260 px/image) of h1pad (8 chunks) and m1pad (2 chunks)
__global__ void ring_zero_kernel(unsigned short* __restrict__ h1h, unsigned short* __restrict__ h1l,
                                 unsigned short* __restrict__ m1h, unsigned short* __restrict__ m1l)
{
    int bid = blockIdx.x;           // b*260 + r
    int b = bid / 260;
    int r = bid - b * 260;
    int i, j;
    if (r < 66)       { i = 0;        j = r; }
    else if (r < 132) { i = 65;       j = r - 66; }
    else if (r < 196) { i = r - 131;  j = 0; }     // rows 1..64
    else              { i = r - 195;  j = 65; }
    size_t pp = (size_t)i * 66 + j;
    int t = threadIdx.x;
    int ch = t >> 5, sub = t & 31;
    size_t o = ((size_t)(ch * 4 + b) * 4356 + pp) * 32 + sub;
    h1h[o] = 0; h1l[o] = 0;
    if (t < 64) { m1h[o] = 0; m1l[o] = 0; }
}

__global__ void zerofill_kernel(uint4* __restrict__ p, int n)
{
    int i = blockIdx.x * 256 + threadIdx.x;
    if (i < n) p[i] = make_uint4(0u, 0u, 0u, 0u);
}

// merged weight prep. OIHW fp32 -> [g][ch][tap][OCPAD][32] split bf16 (zero-pad oc)
__global__ void prep_w_all_kernel(
    const float* __restrict__ w1, const float* __restrict__ w2,
    const float* __restrict__ w3, const float* __restrict__ w4,
    unsigned short* __restrict__ w1h, unsigned short* __restrict__ w1l,
    unsigned short* __restrict__ w2h, unsigned short* __restrict__ w2l,
    unsigned short* __restrict__ w3h, unsigned short* __restrict__ w3l,
    unsigned short* __restrict__ w4h, unsigned short* __restrict__ w4l)
{
    const int N1 = 147456, N2 = 184320, N3 = 147456, N4 = 27648;
    int idx = blockIdx.x * 256 + threadIdx.x;
    const float* w; unsigned short *outh, *outl;
    int ocpad, oc_real, ic, base;
    if (idx < N1)                { w = w1; outh = w1h; outl = w1l; ocpad = 64; oc_real = 64; ic = 64;  base = 0; }
    else if (idx < N1 + N2)      { w = w2; outh = w2h; outl = w2l; ocpad = 80; oc_real = 72; ic = 256; base = N1; }
    else if (idx < N1 + N2 + N3) { w = w3; outh = w3h; outl = w3l; ocpad = 64; oc_real = 64; ic = 256; base = N1 + N2; }
    else if (idx < N1 + N2 + N3 + N4) { w = w4; outh = w4h; outl = w4l; ocpad = 48; oc_real = 36; ic = 64; base = N1 + N2 + N3; }
    else return;
    int lidx = idx - base;
    // lidx -> [g][ch][tap][ocp][ici]
    int ici = lidx & 31;
    int t1 = lidx >> 5;
    int ocp = t1 % ocpad;
    int t2 = t1 / ocpad;
    int tap = t2 % 9;
    int t3 = t2 / 9;
    int nch = ic >> 5;
    int ch = t3 % nch;
    int g = t3 / nch;
    float v = 0.f;
    if (ocp < oc_real) {
        int oc = g * oc_real + ocp;
        int icx = ch * 32 + ici;
        v = w[((size_t)oc * ic + icx) * 9 + tap];
    }
    unsigned short h, l; split2(v, &h, &l);
    outh[lidx] = h; outl[lidx] = l;
}

// ---------------- deformable sampling (exact fp32, finalizeB fused) ----------------
// 4 points per wave, 16 lanes per point, float4 gathers (4 channels/lane).
// Reads raw conv partials P2a/P4a and applies bias / sigmoid inline.
__global__ __launch_bounds__(256) void deform_sample(
    const float* __restrict__ x,
    const float* __restrict__ P2a, const float* __restrict__ P4a,
    const float* __restrict__ b2, const float* __restrict__ b4,
    float* __restrict__ out)
{
    int wid = (int)((blockIdx.x * 256u + threadIdx.x) >> 6);   // 0..16383
    int lane = (int)(threadIdx.x & 63u);
    int sub = lane >> 4;         // 0..3: which point
    int li = lane & 15;

    int b = wid >> 12;           // 4096 waves per batch
    int rem = wid & 4095;
    int g = rem >> 10;
    int hw = ((rem & 1023) << 2) + sub;
    int hy = hw >> 6;
    int wx = hw & 63;

    // lanes li<9 of each subwave: offsets (P2a+b2) and modulation sigmoid(P4a+b4)
    float fx = 0.f, fy = 0.f, fm = 0.f;
    if (li < 9) {
        size_t p = (size_t)(b << 12) + hw;
        int c2 = g * 18 + li;
        fx = P2a[p * 80 + c2] + b2[c2];
        fy = P2a[p * 80 + 9 + c2] + b2[9 + c2];
        int c4 = g * 9 + li;
        float mv = P4a[p * 48 + c4] + b4[c4];
        fm = 1.0f / (1.0f + expf(-mv));
    }
    float px = fminf(fmaxf((float)wx + (float)(li % 3 - 1) + fx, 0.f), 63.f);
    float py = fminf(fmaxf((float)hy + (float)(li / 3 - 1) + fy, 0.f), 63.f);
    float x0f = floorf(px), y0f = floorf(py);
    float wxf = px - x0f, wyf = py - y0f;
    int x0 = (int)x0f, y0 = (int)y0f;
    int x1 = min(x0 + 1, 63), y1 = min(y0 + 1, 63);

    // lane li gathers channels g*64 + li*4 .. +3 as float4
    const float4* xb = (const float4*)(x + ((size_t)(b << 12)) * 256 + g * 64 + li * 4);
    float4 acc = make_float4(0.f, 0.f, 0.f, 0.f);
    int sb = sub << 4;
#pragma unroll
    for (int q = 0; q < 9; q++) {
        int src = sb + q;
        int   qx0 = __shfl(x0, src);
        int   qx1 = __shfl(x1, src);
        int   qy0 = __shfl(y0, src);
        int   qy1 = __shfl(y1, src);
        float qwx = __shfl(wxf, src);
        float qwy = __shfl(wyf, src);
        float qm  = __shfl(fm, src);
        float4 v00 = xb[(size_t)(qy0 * 64 + qx0) * 64];
        float4 v01 = xb[(size_t)(qy0 * 64 + qx1) * 64];
        float4 v10 = xb[(size_t)(qy1 * 64 + qx0) * 64];
        float4 v11 = xb[(size_t)(qy1 * 64 + qx1) * 64];
        float w00 = (1.f - qwx) * (1.f - qwy);
        float w01 = qwx * (1.f - qwy);
        float w10 = (1.f - qwx) * qwy;
        float w11 = qwx * qwy;
        acc.x += qm * (v00.x * w00 + v01.x * w01 + v10.x * w10 + v11.x * w11);
        acc.y += qm * (v00.y * w00 + v01.y * w01 + v10.y * w10 + v11.y * w11);
        acc.z += qm * (v00.z * w00 + v01.z * w01 + v10.z * w10 + v11.z * w11);
        acc.w += qm * (v00.w * w00 + v01.w * w01 + v10.w * w10 + v11.w * w11);
    }
    const float s = 1.f / 9.f;
    acc.x *= s; acc.y *= s; acc.z *= s; acc.w *= s;
    float4* ob = (float4*)(out + ((size_t)(b << 12) + hw) * 256 + g * 64 + li * 4);
    *ob = acc;
}

extern "C" void kernel_launch(void* const* d_in, const int* in_sizes, int n_in,
                              void* d_out, int out_size, void* d_ws, size_t ws_size,
                              hipStream_t stream)
{
    const float* x      = (const float*)d_in[0];
    const float* off_w1 = (const float*)d_in[1];
    const float* off_b1 = (const float*)d_in[2];
    const float* off_w2 = (const float*)d_in[3];
    const float* off_b2 = (const float*)d_in[4];
    const float* mod_w1 = (const float*)d_in[5];
    const float* mod_b1 = (const float*)d_in[6];
    const float* mod_w2 = (const float*)d_in[7];
    const float* mod_b2 = (const float*)d_in[8];

    // ws layout (ushort units; all counts multiple of 8 -> 16B alignment holds)
    const size_t XP = 4u * 4356u * 256u;   // 4,460,544 (8 chunks x 4 b x 4356 x 32)
    const size_t MP = 4u * 4356u * 64u;    // 1,115,136 (2 chunks)
    const size_t W1 = 4u * 2u * 9u * 64u * 32u;  // 147,456
    const size_t W2 = 8u * 9u * 80u * 32u;       // 184,320
    const size_t W3 = 8u * 9u * 64u * 32u;       // 147,456
    const size_t W4 = 2u * 9u * 48u * 32u;       // 27,648

    unsigned short* ws = (unsigned short*)d_ws;
    size_t o = 0;
    unsigned short* xph = ws + o; o += XP;
    unsigned short* xpl = ws + o; o += XP;
    unsigned short* h1h = ws + o; o += XP;
    unsigned short* h1l = ws + o; o += XP;
    unsigned short* m1h = ws + o; o += MP;
    unsigned short* m1l = ws + o; o += MP;
    unsigned short* w1h = ws + o; o += W1;
    unsigned short* w1l = ws + o; o += W1;
    unsigned short* w2h = ws + o; o += W2;
    unsigned short* w2l = ws + o; o += W2;
    unsigned short* w3h = ws + o; o += W3;
    unsigned short* w3l = ws + o; o += W3;
    unsigned short* w4h = ws + o; o += W4;
    unsigned short* w4l = ws + o; o += W4;
    // fp32 accumulators, contiguous so one zerofill covers all three:
    float* fbase = (float*)(ws + o);
    float* P3  = fbase;                              // [4*4096][64] = 1,048,576
    float* P2a = P3 + (size_t)4 * 4096 * 64;         // [4*4096][80] = 1,310,720
    float* P4a = P2a + (size_t)4 * 4096 * 80;        // [4*4096][48] =   786,432
    const size_t ACC_FLOATS = (size_t)4 * 4096 * (64 + 80 + 48);  // 3,145,728
    size_t need_bytes = o * 2 + ACC_FLOATS * 4;      // ~55 MB (ws ~268 MB)
    if (ws_size < need_bytes) return;  // deterministic guard

    // zero all atomic accumulators up front (12.6 MB, one dispatch)
    zerofill_kernel<<<(int)(ACC_FLOATS / 4 + 255) / 256, 256, 0, stream>>>(
        (uint4*)P3, (int)(ACC_FLOATS / 4));
    ring_zero_kernel<<<4 * 260, 256, 0, stream>>>(h1h, h1l, m1h, m1l);
    prep_x_kernel<<<4 * 4356, 256, 0, stream>>>(x, xph, xpl);
    {
        const int NW = 147456 + 184320 + 147456 + 27648;
        prep_w_all_kernel<<<(NW + 255) / 256, 256, 0, stream>>>(
            off_w1, off_w2, mod_w1, mod_w2,
            w1h, w1l, w2h, w2l, w3h, w3l, w4h, w4l);
    }

    convA_kernel<<<dim3(320, 1, 4), 256, 0, stream>>>(xph, xpl, w1h, w1l, off_b1,
                                                      w3h, w3l, h1h, h1l, P3);
    finalizeA_kernel<<<4096, 256, 0, stream>>>(P3, mod_b1, m1h, m1l);
    convB_kernel<<<dim3(288, 1, 4), 256, 0, stream>>>(h1h, h1l, w2h, w2l,
                                                      m1h, m1l, w4h, w4l, P2a, P4a);
    deform_sample<<<4096, 256, 0, stream>>>(x, P2a, P4a, off_b2, mod_b2, (float*)d_out);
}